// Round 1
// baseline (504.634 us; speedup 1.0000x reference)
//
#include <hip/hip_runtime.h>

typedef unsigned short u16;
typedef unsigned int u32;
typedef __attribute__((ext_vector_type(8))) short bf16x8;
typedef __attribute__((ext_vector_type(4))) float f32x4;

#define LCONST __launch_bounds__(256)

__device__ __forceinline__ u16 f2bf(float f) {
  u32 u = __float_as_uint(f);
  u32 r = (u + 0x7FFFu + ((u >> 16) & 1u)) >> 16;
  return (u16)r;
}
__device__ __forceinline__ float bflo(u32 w) { return __uint_as_float(w << 16); }
__device__ __forceinline__ float bfhi(u32 w) { return __uint_as_float(w & 0xFFFF0000u); }
__device__ __forceinline__ float b2f(u16 v) { return __uint_as_float(((u32)v) << 16); }

__device__ __forceinline__ float dot8(uint4 u, const float* q) {
  return q[0]*bflo(u.x) + q[1]*bfhi(u.x) + q[2]*bflo(u.y) + q[3]*bfhi(u.y)
       + q[4]*bflo(u.z) + q[5]*bfhi(u.z) + q[6]*bflo(u.w) + q[7]*bfhi(u.w);
}
__device__ __forceinline__ void fma8(uint4 u, float wt, float* a) {
  a[0] = fmaf(wt, bflo(u.x), a[0]); a[1] = fmaf(wt, bfhi(u.x), a[1]);
  a[2] = fmaf(wt, bflo(u.y), a[2]); a[3] = fmaf(wt, bfhi(u.y), a[3]);
  a[4] = fmaf(wt, bflo(u.z), a[4]); a[5] = fmaf(wt, bfhi(u.z), a[5]);
  a[6] = fmaf(wt, bflo(u.w), a[6]); a[7] = fmaf(wt, bfhi(u.w), a[7]);
}

// ---------------- transpose-cast weights: Wt[n*K+k] = bf16(W[k*N+n]) -------
__global__ LCONST void tcast_kernel(const float* __restrict__ W, u16* __restrict__ Wt,
                                    int K, int N) {
  int idx = blockIdx.x * 256 + threadIdx.x;
  int n = idx / K, k = idx - n * K;
  Wt[idx] = f2bf(W[(size_t)k * N + n]);
}

// ---------------- mean over L ----------------------------------------------
__global__ LCONST void mean_part_kernel(const float* __restrict__ e, float* __restrict__ part) {
  int blk = blockIdx.x;            // b*32 + c
  int b = blk >> 5, c = blk & 31;
  int d = threadIdx.x;
  const float* p = e + ((size_t)b * 2048 + (size_t)c * 64) * 256 + d;
  float s = 0.f;
  #pragma unroll 8
  for (int i = 0; i < 64; i++) s += p[(size_t)i * 256];
  part[(size_t)blk * 256 + d] = s;
}
__global__ LCONST void mean_fin_kernel(const float* __restrict__ part, float* __restrict__ s0) {
  int b = blockIdx.x, d = threadIdx.x;
  float s = 0.f;
  #pragma unroll
  for (int c = 0; c < 32; c++) s += part[((size_t)b * 32 + c) * 256 + d];
  s0[b * 256 + d] = s * (1.f / 2048.f);
}

// ---------------- bf16 MFMA GEMM: C = A(MxK) * Bt^T + bias -----------------
// Bt is N x K row-major bf16 (pre-transposed weight). Tile 128x64, BK=32.
template <typename AT, typename OT, bool RELU, bool BIAS>
__global__ LCONST void gemm_kernel(const AT* __restrict__ A, const u16* __restrict__ Bt,
                                   const float* __restrict__ bias, OT* __restrict__ C,
                                   int M, int N, int K) {
  __shared__ __align__(16) u16 As[128 * 32];
  __shared__ __align__(16) u16 Bs[64 * 32];
  const int tid = threadIdx.x;
  const int lane = tid & 63;
  const int wid = tid >> 6;
  const int wm = wid >> 1, wn = wid & 1;
  const int m0 = blockIdx.x * 128, n0 = blockIdx.y * 64;

  f32x4 acc[4][2] = {};
  const int nk = K >> 5;
  for (int kt = 0; kt < nk; kt++) {
    const int k0 = kt << 5;
    if constexpr (sizeof(AT) == 4) {           // f32 A: cast on load
      #pragma unroll
      for (int it = 0; it < 4; it++) {
        int c = tid + it * 256;
        int row = c >> 3, kp = (c & 7) << 2;
        float4 f = *(const float4*)(A + (size_t)(m0 + row) * K + k0 + kp);
        ushort4 h;
        h.x = f2bf(f.x); h.y = f2bf(f.y); h.z = f2bf(f.z); h.w = f2bf(f.w);
        *(ushort4*)&As[row * 32 + kp] = h;
      }
    } else {                                   // bf16 A: straight copy
      #pragma unroll
      for (int it = 0; it < 2; it++) {
        int c = tid + it * 256;
        int row = c >> 2, kp = (c & 3) << 3;
        *(uint4*)&As[row * 32 + kp] = *(const uint4*)(A + (size_t)(m0 + row) * K + k0 + kp);
      }
    }
    {
      int row = tid >> 2, kp = (tid & 3) << 3;
      *(uint4*)&Bs[row * 32 + kp] = *(const uint4*)(Bt + (size_t)(n0 + row) * K + k0 + kp);
    }
    __syncthreads();
    bf16x8 af[4], bf[2];
    #pragma unroll
    for (int m = 0; m < 4; m++)
      af[m] = *(const bf16x8*)&As[(wm * 64 + m * 16 + (lane & 15)) * 32 + (lane >> 4) * 8];
    #pragma unroll
    for (int n = 0; n < 2; n++)
      bf[n] = *(const bf16x8*)&Bs[(wn * 32 + n * 16 + (lane & 15)) * 32 + (lane >> 4) * 8];
    #pragma unroll
    for (int m = 0; m < 4; m++)
      #pragma unroll
      for (int n = 0; n < 2; n++)
        acc[m][n] = __builtin_amdgcn_mfma_f32_16x16x32_bf16(af[m], bf[n], acc[m][n], 0, 0, 0);
    __syncthreads();
  }
  // epilogue: C/D layout col = lane&15, row = (lane>>4)*4 + reg
  #pragma unroll
  for (int m = 0; m < 4; m++) {
    #pragma unroll
    for (int n = 0; n < 2; n++) {
      #pragma unroll
      for (int r = 0; r < 4; r++) {
        int row = m0 + wm * 64 + m * 16 + (lane >> 4) * 4 + r;
        int col = n0 + wn * 32 + n * 16 + (lane & 15);
        float v = acc[m][n][r];
        if constexpr (BIAS) v += bias[col];
        if constexpr (RELU) v = fmaxf(v, 0.f);
        if constexpr (sizeof(OT) == 4) C[(size_t)row * N + col] = v;
        else                           C[(size_t)row * N + col] = (OT)f2bf(v);
      }
    }
  }
}

// ---------------- small f32 GEMM for s-vectors: Y(Bx256) = X @ W + bias ----
template <bool RELU, bool BIAS>
__global__ LCONST void sgemm_kernel(const float* __restrict__ X, const float* __restrict__ W,
                                    const float* __restrict__ bias, float* __restrict__ Y) {
  int b = blockIdx.x, tid = threadIdx.x;
  const float* xr = X + b * 256;
  float acc = 0.f;
  #pragma unroll 4
  for (int d = 0; d < 256; d++) acc = fmaf(xr[d], W[(size_t)d * 256 + tid], acc);
  if constexpr (BIAS) acc += bias[tid];
  if constexpr (RELU) acc = fmaxf(acc, 0.f);
  Y[b * 256 + tid] = acc;
}

// ---------------- fused 5-key per-token attention (MHA1 core) --------------
__global__ LCONST void attn1_kernel(const u16* __restrict__ hq, const u16* __restrict__ pk,
                                    const u16* __restrict__ pv, const u16* __restrict__ ek,
                                    const u16* __restrict__ ev, const float* __restrict__ skp,
                                    const float* __restrict__ svp, u16* __restrict__ outp) {
  int t = blockIdx.x * 256 + threadIdx.x;     // B*L*H threads
  int h = t & 7;
  size_t token = (size_t)(t >> 3);
  int b = (int)(token >> 11);
  int i = (int)(token & 2047);
  size_t tb = (size_t)b << 11;
  size_t ip = tb + ((i + 1) & 2047);
  size_t im = tb + ((i + 2047) & 2047);
  const int off = h * 32;

  float qf[32];
  {
    const u16* q = hq + token * 256 + off;
    #pragma unroll
    for (int c = 0; c < 4; c++) {
      uint4 u = *(const uint4*)(q + c * 8);
      qf[c*8+0] = bflo(u.x); qf[c*8+1] = bfhi(u.x);
      qf[c*8+2] = bflo(u.y); qf[c*8+3] = bfhi(u.y);
      qf[c*8+4] = bflo(u.z); qf[c*8+5] = bfhi(u.z);
      qf[c*8+6] = bflo(u.w); qf[c*8+7] = bfhi(u.w);
    }
  }
  const u16* kr0 = pk + ip * 256 + off;
  const u16* kr1 = pk + token * 256 + off;
  const u16* kr2 = pk + im * 256 + off;
  const u16* kr3 = ek + token * 256 + off;
  float lg[5];
  {
    float d0 = 0, d1 = 0, d2 = 0, d3 = 0;
    #pragma unroll
    for (int cc = 0; cc < 4; cc++) {
      d0 += dot8(*(const uint4*)(kr0 + cc * 8), qf + cc * 8);
      d1 += dot8(*(const uint4*)(kr1 + cc * 8), qf + cc * 8);
      d2 += dot8(*(const uint4*)(kr2 + cc * 8), qf + cc * 8);
      d3 += dot8(*(const uint4*)(kr3 + cc * 8), qf + cc * 8);
    }
    lg[0] = d0; lg[1] = d1; lg[2] = d2; lg[3] = d3;
    float d4 = 0;
    const float* s = skp + b * 256 + off;
    #pragma unroll
    for (int j = 0; j < 32; j++) d4 = fmaf(qf[j], s[j], d4);
    lg[4] = d4;
  }
  const float sc = 0.17677669529663687f;      // 1/sqrt(32)
  float m = lg[0];
  #pragma unroll
  for (int c = 1; c < 5; c++) m = fmaxf(m, lg[c]);
  float w[5], den = 0.f;
  #pragma unroll
  for (int c = 0; c < 5; c++) { w[c] = __expf((lg[c] - m) * sc); den += w[c]; }

  float a[32];
  #pragma unroll
  for (int j = 0; j < 32; j++) a[j] = 0.f;
  const u16* vr0 = pv + ip * 256 + off;
  const u16* vr1 = pv + token * 256 + off;
  const u16* vr2 = pv + im * 256 + off;
  const u16* vr3 = ev + token * 256 + off;
  #pragma unroll
  for (int cc = 0; cc < 4; cc++) {
    fma8(*(const uint4*)(vr0 + cc * 8), w[0], a + cc * 8);
    fma8(*(const uint4*)(vr1 + cc * 8), w[1], a + cc * 8);
    fma8(*(const uint4*)(vr2 + cc * 8), w[2], a + cc * 8);
    fma8(*(const uint4*)(vr3 + cc * 8), w[3], a + cc * 8);
  }
  {
    const float* s = svp + b * 256 + off;
    #pragma unroll
    for (int j = 0; j < 32; j++) a[j] = fmaf(w[4], s[j], a[j]);
  }
  float inv = 1.f / den;
  u16* o = outp + token * 256 + off;
  #pragma unroll
  for (int c = 0; c < 4; c++) {
    uint4 u;
    u.x = (u32)f2bf(a[c*8+0] * inv) | ((u32)f2bf(a[c*8+1] * inv) << 16);
    u.y = (u32)f2bf(a[c*8+2] * inv) | ((u32)f2bf(a[c*8+3] * inv) << 16);
    u.z = (u32)f2bf(a[c*8+4] * inv) | ((u32)f2bf(a[c*8+5] * inv) << 16);
    u.w = (u32)f2bf(a[c*8+6] * inv) | ((u32)f2bf(a[c*8+7] * inv) << 16);
    *(uint4*)(o + c * 8) = u;
  }
}

// ---------------- MHA2: block per (b,h), softmax over 2049 keys ------------
__global__ LCONST void mha2_kernel(const float* __restrict__ sqp, const float* __restrict__ skp,
                                   const float* __restrict__ svp, const u16* __restrict__ pk,
                                   const u16* __restrict__ pv, float* __restrict__ attn2) {
  __shared__ float lgs[2049];
  __shared__ float rmax[4];
  __shared__ float rsum[4];
  __shared__ float racc[4][32];
  const int bh = blockIdx.x;
  const int b = bh >> 3, h = bh & 7;
  const int tid = threadIdx.x;
  const int lane = tid & 63, wid = tid >> 6;
  const int off = h * 32;
  const float sc = 0.17677669529663687f;

  float qf[32];
  {
    const float* q = sqp + b * 256 + off;
    #pragma unroll
    for (int j = 0; j < 32; j++) qf[j] = q[j];
  }
  float lmax = -1e30f;
  for (int idx = tid; idx < 2049; idx += 256) {
    float d = 0.f;
    if (idx == 0) {
      const float* k = skp + b * 256 + off;
      #pragma unroll
      for (int j = 0; j < 32; j++) d = fmaf(qf[j], k[j], d);
    } else {
      const u16* k = pk + ((size_t)b * 2048 + (idx - 1)) * 256 + off;
      #pragma unroll
      for (int cc = 0; cc < 4; cc++) d += dot8(*(const uint4*)(k + cc * 8), qf + cc * 8);
    }
    d *= sc;
    lgs[idx] = d;
    lmax = fmaxf(lmax, d);
  }
  #pragma unroll
  for (int o = 32; o; o >>= 1) lmax = fmaxf(lmax, __shfl_down(lmax, o));
  if (lane == 0) rmax[wid] = lmax;
  __syncthreads();
  const float M = fmaxf(fmaxf(rmax[0], rmax[1]), fmaxf(rmax[2], rmax[3]));

  float lsum = 0.f;
  float a[32];
  #pragma unroll
  for (int j = 0; j < 32; j++) a[j] = 0.f;
  for (int idx = tid; idx < 2049; idx += 256) {
    float wt = __expf(lgs[idx] - M);
    lsum += wt;
    if (idx == 0) {
      const float* v = svp + b * 256 + off;
      #pragma unroll
      for (int j = 0; j < 32; j++) a[j] = fmaf(wt, v[j], a[j]);
    } else {
      const u16* v = pv + ((size_t)b * 2048 + (idx - 1)) * 256 + off;
      #pragma unroll
      for (int cc = 0; cc < 4; cc++) fma8(*(const uint4*)(v + cc * 8), wt, a + cc * 8);
    }
  }
  #pragma unroll
  for (int o = 32; o; o >>= 1) lsum += __shfl_down(lsum, o);
  if (lane == 0) rsum[wid] = lsum;
  #pragma unroll
  for (int j = 0; j < 32; j++) {
    float v = a[j];
    #pragma unroll
    for (int o = 32; o; o >>= 1) v += __shfl_down(v, o);
    if (lane == 0) racc[wid][j] = v;
  }
  __syncthreads();
  if (tid < 32) {
    float den = rsum[0] + rsum[1] + rsum[2] + rsum[3];
    float o = racc[0][tid] + racc[1][tid] + racc[2][tid] + racc[3][tid];
    attn2[b * 256 + off + tid] = o / den;
  }
}

// ---------------- fused layernorms (wave per row) --------------------------
__global__ LCONST void ln1_kernel(const float* __restrict__ e, const u16* __restrict__ h,
                                  const float* __restrict__ g, const float* __restrict__ be,
                                  float* __restrict__ out) {
  int row = blockIdx.x * 4 + (threadIdx.x >> 6);
  int lane = threadIdx.x & 63;
  size_t base = (size_t)row * 256 + lane * 4;
  float4 ef = *(const float4*)(e + base);
  ushort4 hu = *(const ushort4*)(h + base);
  float x0 = ef.x + b2f(hu.x), x1 = ef.y + b2f(hu.y);
  float x2 = ef.z + b2f(hu.z), x3 = ef.w + b2f(hu.w);
  float s = x0 + x1 + x2 + x3;
  #pragma unroll
  for (int o = 32; o; o >>= 1) s += __shfl_xor(s, o);
  float mu = s * (1.f / 256.f);
  float d0 = x0 - mu, d1 = x1 - mu, d2 = x2 - mu, d3 = x3 - mu;
  float q = d0*d0 + d1*d1 + d2*d2 + d3*d3;
  #pragma unroll
  for (int o = 32; o; o >>= 1) q += __shfl_xor(q, o);
  float rs = rsqrtf(q * (1.f / 256.f) + 1e-6f);
  int gi = lane * 4;
  float4 r;
  r.x = g[gi+0]*d0*rs + be[gi+0]; r.y = g[gi+1]*d1*rs + be[gi+1];
  r.z = g[gi+2]*d2*rs + be[gi+2]; r.w = g[gi+3]*d3*rs + be[gi+3];
  *(float4*)(out + base) = r;
}

__global__ LCONST void ln2_kernel(const float* __restrict__ out1, const float* __restrict__ g,
                                  const float* __restrict__ be, float* __restrict__ io) {
  int row = blockIdx.x * 4 + (threadIdx.x >> 6);
  int lane = threadIdx.x & 63;
  size_t base = (size_t)row * 256 + lane * 4;
  float4 af = *(const float4*)(out1 + base);
  float4 bf = *(const float4*)(io + base);
  float x0 = af.x + bf.x, x1 = af.y + bf.y, x2 = af.z + bf.z, x3 = af.w + bf.w;
  float s = x0 + x1 + x2 + x3;
  #pragma unroll
  for (int o = 32; o; o >>= 1) s += __shfl_xor(s, o);
  float mu = s * (1.f / 256.f);
  float d0 = x0 - mu, d1 = x1 - mu, d2 = x2 - mu, d3 = x3 - mu;
  float q = d0*d0 + d1*d1 + d2*d2 + d3*d3;
  #pragma unroll
  for (int o = 32; o; o >>= 1) q += __shfl_xor(q, o);
  float rs = rsqrtf(q * (1.f / 256.f) + 1e-6f);
  int gi = lane * 4;
  float4 r;
  r.x = g[gi+0]*d0*rs + be[gi+0]; r.y = g[gi+1]*d1*rs + be[gi+1];
  r.z = g[gi+2]*d2*rs + be[gi+2]; r.w = g[gi+3]*d3*rs + be[gi+3];
  *(float4*)(io + base) = r;
}

// ===========================================================================
extern "C" void kernel_launch(void* const* d_in, const int* in_sizes, int n_in,
                              void* d_out, int out_size, void* d_ws, size_t ws_size,
                              hipStream_t stream) {
  const float* e   = (const float*)d_in[0];
  const float* Wq  = (const float*)d_in[1];
  const float* Wk  = (const float*)d_in[2];
  const float* Wv  = (const float*)d_in[3];
  const float* Wo  = (const float*)d_in[4];
  const float* bo  = (const float*)d_in[5];
  const float* W1  = (const float*)d_in[6];
  const float* b1  = (const float*)d_in[7];
  const float* W2  = (const float*)d_in[8];
  const float* b2  = (const float*)d_in[9];
  const float* g1  = (const float*)d_in[10];
  const float* be1 = (const float*)d_in[11];
  const float* g2  = (const float*)d_in[12];
  const float* be2 = (const float*)d_in[13];

  char* wsb = (char*)d_ws;
  size_t off = 0;
  auto alc = [&](size_t n) { void* p = wsb + off; off += (n + 255) & ~(size_t)255; return p; };
  u16* Wq_t = (u16*)alc(65536 * 2);
  u16* Wk_t = (u16*)alc(65536 * 2);
  u16* Wv_t = (u16*)alc(65536 * 2);
  u16* Wo_t = (u16*)alc(65536 * 2);
  u16* W1_t = (u16*)alc(262144 * 2);
  u16* W2_t = (u16*)alc(262144 * 2);
  float* sA   = (float*)alc(4096 * 4);
  float* sB   = (float*)alc(4096 * 4);
  float* sqp  = (float*)alc(4096 * 4);
  float* skp  = (float*)alc(4096 * 4);
  float* svp  = (float*)alc(4096 * 4);
  float* attn2 = (float*)alc(4096 * 4);
  float* part = (float*)alc(524288);
  u16* regA = (u16*)alc(4ull * 16777216);      // ek | ev | pk | pv   (later: ffn1)
  u16* ek = regA, *ev = regA + 8388608, *pk = regA + 2ull * 8388608, *pv = regA + 3ull * 8388608;
  u16* regB = (u16*)alc(2ull * 16777216);      // hq | attn_out       (later: out1 f32)
  u16* hq = regB, *ao = regB + 8388608;
  u16* hbuf = (u16*)alc(16777216);             // h (bf16)
  u16* ffn1 = regA;
  float* out1 = (float*)regB;

  const int M = 32768;
  float* outp = (float*)d_out;
  float* s_out = outp + 8388608;
  dim3 g256(M / 128, 4), g1024(M / 128, 16);

  // weights -> bf16 transposed
  tcast_kernel<<<256, 256, 0, stream>>>(Wq, Wq_t, 256, 256);
  tcast_kernel<<<256, 256, 0, stream>>>(Wk, Wk_t, 256, 256);
  tcast_kernel<<<256, 256, 0, stream>>>(Wv, Wv_t, 256, 256);
  tcast_kernel<<<256, 256, 0, stream>>>(Wo, Wo_t, 256, 256);
  tcast_kernel<<<1024, 256, 0, stream>>>(W1, W1_t, 256, 1024);
  tcast_kernel<<<1024, 256, 0, stream>>>(W2, W2_t, 1024, 256);
  // s0 = mean_L(e)
  mean_part_kernel<<<512, 256, 0, stream>>>(e, part);
  mean_fin_kernel<<<16, 256, 0, stream>>>(part, sA);
  // e projections (reused both cycles; cycle-1 h == e so these double as pk/pv)
  gemm_kernel<float, u16, false, false><<<g256, 256, 0, stream>>>(e, Wk_t, nullptr, ek, M, 256, 256);
  gemm_kernel<float, u16, false, false><<<g256, 256, 0, stream>>>(e, Wv_t, nullptr, ev, M, 256, 256);

  // ---------------- cycle 1 (h = e, s = sA) ----------------
  sgemm_kernel<false, false><<<16, 256, 0, stream>>>(sA, Wq, nullptr, sqp);
  sgemm_kernel<false, false><<<16, 256, 0, stream>>>(sA, Wk, nullptr, skp);
  sgemm_kernel<false, false><<<16, 256, 0, stream>>>(sA, Wv, nullptr, svp);
  gemm_kernel<float, u16, false, false><<<g256, 256, 0, stream>>>(e, Wq_t, nullptr, hq, M, 256, 256);
  attn1_kernel<<<1024, 256, 0, stream>>>(hq, ek, ev, ek, ev, skp, svp, ao);
  gemm_kernel<u16, u16, true, true><<<g256, 256, 0, stream>>>(ao, Wo_t, bo, hbuf, M, 256, 256);
  gemm_kernel<u16, u16, false, false><<<g256, 256, 0, stream>>>(hbuf, Wk_t, nullptr, pk, M, 256, 256);
  gemm_kernel<u16, u16, false, false><<<g256, 256, 0, stream>>>(hbuf, Wv_t, nullptr, pv, M, 256, 256);
  mha2_kernel<<<128, 256, 0, stream>>>(sqp, skp, svp, pk, pv, attn2);
  sgemm_kernel<true, true><<<16, 256, 0, stream>>>(attn2, Wo, bo, sB);

  // ---------------- cycle 2 (h = hbuf, s = sB) ----------------
  sgemm_kernel<false, false><<<16, 256, 0, stream>>>(sB, Wq, nullptr, sqp);
  sgemm_kernel<false, false><<<16, 256, 0, stream>>>(sB, Wk, nullptr, skp);
  sgemm_kernel<false, false><<<16, 256, 0, stream>>>(sB, Wv, nullptr, svp);
  gemm_kernel<u16, u16, false, false><<<g256, 256, 0, stream>>>(hbuf, Wq_t, nullptr, hq, M, 256, 256);
  attn1_kernel<<<1024, 256, 0, stream>>>(hq, pk, pv, ek, ev, skp, svp, ao);
  gemm_kernel<u16, u16, true, true><<<g256, 256, 0, stream>>>(ao, Wo_t, bo, hbuf, M, 256, 256);
  gemm_kernel<u16, u16, false, false><<<g256, 256, 0, stream>>>(hbuf, Wk_t, nullptr, pk, M, 256, 256);
  gemm_kernel<u16, u16, false, false><<<g256, 256, 0, stream>>>(hbuf, Wv_t, nullptr, pv, M, 256, 256);
  mha2_kernel<<<128, 256, 0, stream>>>(sqp, skp, svp, pk, pv, attn2);
  sgemm_kernel<true, true><<<16, 256, 0, stream>>>(attn2, Wo, bo, s_out);   // s output

  // ---------------- epilogue: LN1 -> FFN -> LN2 ----------------
  ln1_kernel<<<8192, 256, 0, stream>>>(e, hbuf, g1, be1, out1);
  gemm_kernel<float, u16, true, true><<<g1024, 256, 0, stream>>>(out1, W1_t, b1, ffn1, M, 1024, 256);
  gemm_kernel<u16, float, false, true><<<g256, 256, 0, stream>>>(ffn1, W2_t, b2, outp, M, 256, 1024);
  ln2_kernel<<<8192, 256, 0, stream>>>(out1, g2, be2, outp);
  (void)in_sizes; (void)n_in; (void)out_size; (void)ws_size;
}

// Round 2
// 367.373 us; speedup vs baseline: 1.3736x; 1.3736x over previous
//
#include <hip/hip_runtime.h>

typedef unsigned short u16;
typedef unsigned int u32;
typedef __attribute__((ext_vector_type(8))) short bf16x8;
typedef __attribute__((ext_vector_type(4))) float f32x4;

#define LCONST __launch_bounds__(256)

__device__ __forceinline__ u16 f2bf(float f) {
  u32 u = __float_as_uint(f);
  u32 r = (u + 0x7FFFu + ((u >> 16) & 1u)) >> 16;
  return (u16)r;
}
__device__ __forceinline__ float bflo(u32 w) { return __uint_as_float(w << 16); }
__device__ __forceinline__ float bfhi(u32 w) { return __uint_as_float(w & 0xFFFF0000u); }
__device__ __forceinline__ float b2f(u16 v) { return __uint_as_float(((u32)v) << 16); }

__device__ __forceinline__ float dot8(uint4 u, const float* q) {
  return q[0]*bflo(u.x) + q[1]*bfhi(u.x) + q[2]*bflo(u.y) + q[3]*bfhi(u.y)
       + q[4]*bflo(u.z) + q[5]*bfhi(u.z) + q[6]*bflo(u.w) + q[7]*bfhi(u.w);
}
__device__ __forceinline__ void fma8(uint4 u, float wt, float* a) {
  a[0] = fmaf(wt, bflo(u.x), a[0]); a[1] = fmaf(wt, bfhi(u.x), a[1]);
  a[2] = fmaf(wt, bflo(u.y), a[2]); a[3] = fmaf(wt, bfhi(u.y), a[3]);
  a[4] = fmaf(wt, bflo(u.z), a[4]); a[5] = fmaf(wt, bfhi(u.z), a[5]);
  a[6] = fmaf(wt, bflo(u.w), a[6]); a[7] = fmaf(wt, bfhi(u.w), a[7]);
}

// async global -> LDS, 16 bytes per lane. LDS dest = wave-uniform base + lane*16.
__device__ __forceinline__ void gload16(const u16* g, u16* l) {
  __builtin_amdgcn_global_load_lds(
      (const __attribute__((address_space(1))) unsigned int*)g,
      (__attribute__((address_space(3))) unsigned int*)l, 16, 0, 0);
}

// ---------------- transpose-cast weights: Wt[n*K+k] = bf16(W[k*N+n]) -------
__global__ LCONST void tcast_kernel(const float* __restrict__ W, u16* __restrict__ Wt,
                                    int K, int N) {
  int idx = blockIdx.x * 256 + threadIdx.x;
  int n = idx / K, k = idx - n * K;
  Wt[idx] = f2bf(W[(size_t)k * N + n]);
}

// ---------------- mean over L (also casts e -> bf16) -----------------------
__global__ LCONST void mean_part_kernel(const float* __restrict__ e, float* __restrict__ part,
                                        u16* __restrict__ ebf) {
  int blk = blockIdx.x;            // b*32 + c
  int b = blk >> 5, c = blk & 31;
  int d = threadIdx.x;
  size_t base = ((size_t)b * 2048 + (size_t)c * 64) * 256 + d;
  float s = 0.f;
  #pragma unroll 8
  for (int i = 0; i < 64; i++) {
    float v = e[base + (size_t)i * 256];
    s += v;
    ebf[base + (size_t)i * 256] = f2bf(v);
  }
  part[(size_t)blk * 256 + d] = s;
}
__global__ LCONST void mean_fin_kernel(const float* __restrict__ part, float* __restrict__ s0) {
  int b = blockIdx.x, d = threadIdx.x;
  float s = 0.f;
  #pragma unroll
  for (int c = 0; c < 32; c++) s += part[((size_t)b * 32 + c) * 256 + d];
  s0[b * 256 + d] = s * (1.f / 2048.f);
}

// ---------------- MFMA GEMM: C = A(MxK,bf16) * Bt(NxK,bf16)^T --------------
// BM=128, BK=64. BN=128 -> 256 thr (2x2 waves); BN=256 -> 512 thr (2x4 waves).
// LDS XOR-swizzle (slot ^= row&7) applied by pre-swizzling the global source
// (global_load_lds writes linearly) and reading with the swizzled slot.
// EPI: 0 = plain bf16 store routed into 256-wide buffers C0/C1/C2 by col>>8
//      1 = relu(acc+bias) -> bf16 C0 (stride N)
//      2 = Wo+LN1: h=relu(acc+bias)->C0(hbuf); out1=LN(e+h)->C1 (bf16)
//      4 = FFN2+LN2: x=acc+bias+res(bf16); out=LN(x) -> Fout (f32)
template <int BN, int EPI>
__global__ __launch_bounds__((BN == 128) ? 256 : 512)
void gemm2_kernel(const u16* __restrict__ A, const u16* __restrict__ Bt,
                  const float* __restrict__ bias,
                  u16* __restrict__ C0, u16* __restrict__ C1, u16* __restrict__ C2,
                  const float* __restrict__ eres, const u16* __restrict__ resbf,
                  const float* __restrict__ g, const float* __restrict__ be,
                  float* __restrict__ Fout,
                  int M, int N, int K) {
  constexpr int NT = (BN == 128) ? 256 : 512;
  constexpr int WAVES = NT / 64;
  constexpr int WNC = WAVES / 2;            // wave cols
  constexpr int ACH_PW = 16 / WAVES;        // A 1KB-chunks per wave
  constexpr int BCH_PW = (BN / 8) / WAVES;  // B 1KB-chunks per wave
  __shared__ __align__(16) u16 As[128 * 64];
  __shared__ __align__(16) u16 Bs[BN * 64];

  const int tid = threadIdx.x, lane = tid & 63, wid = tid >> 6;
  const int wm = wid / WNC, wn = wid % WNC;

  // XCD-chunked swizzle (grid always multiple of 8), row-major (mb,nb) decode
  const int ncol = N / BN;
  const int nwg = gridDim.x;
  const int bid = blockIdx.x;
  const int swz = (bid & 7) * (nwg >> 3) + (bid >> 3);
  const int mb = swz / ncol, nb = swz - mb * ncol;
  const int m0 = mb * 128, n0 = nb * BN;

  const int lrow8 = lane >> 3;              // row within 8-row chunk
  const int cg = (lane & 7) ^ lrow8;        // pre-swizzled global 16B-slot

  f32x4 acc[4][4] = {};
  for (int kt = 0; kt < K; kt += 64) {
    #pragma unroll
    for (int it = 0; it < ACH_PW; it++) {
      int ca = wid * ACH_PW + it;
      int row = ca * 8 + lrow8;
      gload16(A + (size_t)(m0 + row) * K + kt + cg * 8, (u16*)As + ca * 512);
    }
    #pragma unroll
    for (int it = 0; it < BCH_PW; it++) {
      int cb = wid * BCH_PW + it;
      int row = cb * 8 + lrow8;
      gload16(Bt + (size_t)(n0 + row) * K + kt + cg * 8, (u16*)Bs + cb * 512);
    }
    __syncthreads();
    const int lr = lane & 15, hi = lane >> 4;
    #pragma unroll
    for (int kk = 0; kk < 2; kk++) {
      const int slot = (kk * 4 + hi) ^ (lr & 7);
      bf16x8 af[4], bfr[4];
      #pragma unroll
      for (int m = 0; m < 4; m++)
        af[m] = *(const bf16x8*)&As[(wm * 64 + m * 16 + lr) * 64 + slot * 8];
      #pragma unroll
      for (int n = 0; n < 4; n++)
        bfr[n] = *(const bf16x8*)&Bs[(wn * 64 + n * 16 + lr) * 64 + slot * 8];
      #pragma unroll
      for (int m = 0; m < 4; m++)
        #pragma unroll
        for (int n = 0; n < 4; n++)
          acc[m][n] = __builtin_amdgcn_mfma_f32_16x16x32_bf16(af[m], bfr[n], acc[m][n], 0, 0, 0);
    }
    __syncthreads();
  }

  const int lr = lane & 15, hi = lane >> 4;
  if constexpr (EPI == 0) {
    const int bsel = n0 >> 8;
    u16* C = (bsel == 0) ? C0 : ((bsel == 1) ? C1 : C2);
    const int nbase = n0 & 255;
    #pragma unroll
    for (int m = 0; m < 4; m++)
      #pragma unroll
      for (int n = 0; n < 4; n++)
        #pragma unroll
        for (int r = 0; r < 4; r++) {
          int row = m0 + wm * 64 + m * 16 + hi * 4 + r;
          int col = nbase + wn * 64 + n * 16 + lr;
          C[(size_t)row * 256 + col] = f2bf(acc[m][n][r]);
        }
  } else if constexpr (EPI == 1) {
    #pragma unroll
    for (int m = 0; m < 4; m++)
      #pragma unroll
      for (int n = 0; n < 4; n++)
        #pragma unroll
        for (int r = 0; r < 4; r++) {
          int row = m0 + wm * 64 + m * 16 + hi * 4 + r;
          int col = n0 + wn * 64 + n * 16 + lr;
          float v = fmaxf(acc[m][n][r] + bias[col], 0.f);
          C0[(size_t)row * N + col] = f2bf(v);
        }
  } else {  // EPI 2 / 4: full-row (BN=256) LN epilogues
    __shared__ float rsum[128], rsq[128];
    if (tid < 128) { rsum[tid] = 0.f; rsq[tid] = 0.f; }
    __syncthreads();
    #pragma unroll
    for (int m = 0; m < 4; m++)
      #pragma unroll
      for (int n = 0; n < 4; n++)
        #pragma unroll
        for (int r = 0; r < 4; r++) {
          int rl = wm * 64 + m * 16 + hi * 4 + r;
          int col = wn * 64 + n * 16 + lr;
          size_t gi = (size_t)(m0 + rl) * 256 + col;
          float v = acc[m][n][r] + bias[col];
          float x;
          if constexpr (EPI == 2) {
            v = fmaxf(v, 0.f);
            C0[gi] = f2bf(v);          // hbuf (h2)
            x = eres[gi] + v;          // e + h
          } else {
            x = b2f(resbf[gi]) + v;    // out1 + ffn
          }
          acc[m][n][r] = x;
        }
    #pragma unroll
    for (int m = 0; m < 4; m++)
      #pragma unroll
      for (int r = 0; r < 4; r++) {
        float s = 0.f, q = 0.f;
        #pragma unroll
        for (int n = 0; n < 4; n++) { float x = acc[m][n][r]; s += x; q += x * x; }
        #pragma unroll
        for (int off = 1; off < 16; off <<= 1) {
          s += __shfl_xor(s, off);
          q += __shfl_xor(q, off);
        }
        if (lr == 0) {
          int rl = wm * 64 + m * 16 + hi * 4 + r;
          atomicAdd(&rsum[rl], s);
          atomicAdd(&rsq[rl], q);
        }
      }
    __syncthreads();
    #pragma unroll
    for (int m = 0; m < 4; m++)
      #pragma unroll
      for (int n = 0; n < 4; n++)
        #pragma unroll
        for (int r = 0; r < 4; r++) {
          int rl = wm * 64 + m * 16 + hi * 4 + r;
          int col = wn * 64 + n * 16 + lr;
          size_t gi = (size_t)(m0 + rl) * 256 + col;
          float mu = rsum[rl] * (1.f / 256.f);
          float var = rsq[rl] * (1.f / 256.f) - mu * mu;
          float rstd = rsqrtf(fmaxf(var, 0.f) + 1e-6f);
          float o = g[col] * (acc[m][n][r] - mu) * rstd + be[col];
          if constexpr (EPI == 2) C1[gi] = f2bf(o);   // out1 bf16
          else                    Fout[gi] = o;       // out2 f32
        }
  }
}

// ---------------- small f32 GEMMs for s-vectors ----------------------------
__global__ LCONST void sgemm3_kernel(const float* __restrict__ X, const float* __restrict__ Wq,
                                     const float* __restrict__ Wk, const float* __restrict__ Wv,
                                     float* __restrict__ Yq, float* __restrict__ Yk,
                                     float* __restrict__ Yv) {
  int b = blockIdx.x, sel = blockIdx.y, tid = threadIdx.x;
  const float* W = (sel == 0) ? Wq : ((sel == 1) ? Wk : Wv);
  float* Y = (sel == 0) ? Yq : ((sel == 1) ? Yk : Yv);
  const float* xr = X + b * 256;
  float acc = 0.f;
  #pragma unroll 4
  for (int d = 0; d < 256; d++) acc = fmaf(xr[d], W[(size_t)d * 256 + tid], acc);
  Y[b * 256 + tid] = acc;
}

template <bool RELU, bool BIAS>
__global__ LCONST void sgemm_kernel(const float* __restrict__ X, const float* __restrict__ W,
                                    const float* __restrict__ bias, float* __restrict__ Y) {
  int b = blockIdx.x, tid = threadIdx.x;
  const float* xr = X + b * 256;
  float acc = 0.f;
  #pragma unroll 4
  for (int d = 0; d < 256; d++) acc = fmaf(xr[d], W[(size_t)d * 256 + tid], acc);
  if constexpr (BIAS) acc += bias[tid];
  if constexpr (RELU) acc = fmaxf(acc, 0.f);
  Y[b * 256 + tid] = acc;
}

// ---------------- fused 5-key per-token attention (MHA1 core) --------------
__global__ LCONST void attn1_kernel(const u16* __restrict__ hq, const u16* __restrict__ pk,
                                    const u16* __restrict__ pv, const u16* __restrict__ ek,
                                    const u16* __restrict__ ev, const float* __restrict__ skp,
                                    const float* __restrict__ svp, u16* __restrict__ outp) {
  int t = blockIdx.x * 256 + threadIdx.x;     // B*L*H threads
  int h = t & 7;
  size_t token = (size_t)(t >> 3);
  int b = (int)(token >> 11);
  int i = (int)(token & 2047);
  size_t tb = (size_t)b << 11;
  size_t ip = tb + ((i + 1) & 2047);
  size_t im = tb + ((i + 2047) & 2047);
  const int off = h * 32;

  float qf[32];
  {
    const u16* q = hq + token * 256 + off;
    #pragma unroll
    for (int c = 0; c < 4; c++) {
      uint4 u = *(const uint4*)(q + c * 8);
      qf[c*8+0] = bflo(u.x); qf[c*8+1] = bfhi(u.x);
      qf[c*8+2] = bflo(u.y); qf[c*8+3] = bfhi(u.y);
      qf[c*8+4] = bflo(u.z); qf[c*8+5] = bfhi(u.z);
      qf[c*8+6] = bflo(u.w); qf[c*8+7] = bfhi(u.w);
    }
  }
  const u16* kr0 = pk + ip * 256 + off;
  const u16* kr1 = pk + token * 256 + off;
  const u16* kr2 = pk + im * 256 + off;
  const u16* kr3 = ek + token * 256 + off;
  float lg[5];
  {
    float d0 = 0, d1 = 0, d2 = 0, d3 = 0;
    #pragma unroll
    for (int cc = 0; cc < 4; cc++) {
      d0 += dot8(*(const uint4*)(kr0 + cc * 8), qf + cc * 8);
      d1 += dot8(*(const uint4*)(kr1 + cc * 8), qf + cc * 8);
      d2 += dot8(*(const uint4*)(kr2 + cc * 8), qf + cc * 8);
      d3 += dot8(*(const uint4*)(kr3 + cc * 8), qf + cc * 8);
    }
    lg[0] = d0; lg[1] = d1; lg[2] = d2; lg[3] = d3;
    float d4 = 0;
    const float* s = skp + b * 256 + off;
    #pragma unroll
    for (int j = 0; j < 32; j++) d4 = fmaf(qf[j], s[j], d4);
    lg[4] = d4;
  }
  const float sc = 0.17677669529663687f;      // 1/sqrt(32)
  float m = lg[0];
  #pragma unroll
  for (int c = 1; c < 5; c++) m = fmaxf(m, lg[c]);
  float w[5], den = 0.f;
  #pragma unroll
  for (int c = 0; c < 5; c++) { w[c] = __expf((lg[c] - m) * sc); den += w[c]; }

  float a[32];
  #pragma unroll
  for (int j = 0; j < 32; j++) a[j] = 0.f;
  const u16* vr0 = pv + ip * 256 + off;
  const u16* vr1 = pv + token * 256 + off;
  const u16* vr2 = pv + im * 256 + off;
  const u16* vr3 = ev + token * 256 + off;
  #pragma unroll
  for (int cc = 0; cc < 4; cc++) {
    fma8(*(const uint4*)(vr0 + cc * 8), w[0], a + cc * 8);
    fma8(*(const uint4*)(vr1 + cc * 8), w[1], a + cc * 8);
    fma8(*(const uint4*)(vr2 + cc * 8), w[2], a + cc * 8);
    fma8(*(const uint4*)(vr3 + cc * 8), w[3], a + cc * 8);
  }
  {
    const float* s = svp + b * 256 + off;
    #pragma unroll
    for (int j = 0; j < 32; j++) a[j] = fmaf(w[4], s[j], a[j]);
  }
  float inv = 1.f / den;
  u16* o = outp + token * 256 + off;
  #pragma unroll
  for (int c = 0; c < 4; c++) {
    uint4 u;
    u.x = (u32)f2bf(a[c*8+0] * inv) | ((u32)f2bf(a[c*8+1] * inv) << 16);
    u.y = (u32)f2bf(a[c*8+2] * inv) | ((u32)f2bf(a[c*8+3] * inv) << 16);
    u.z = (u32)f2bf(a[c*8+4] * inv) | ((u32)f2bf(a[c*8+5] * inv) << 16);
    u.w = (u32)f2bf(a[c*8+6] * inv) | ((u32)f2bf(a[c*8+7] * inv) << 16);
    *(uint4*)(o + c * 8) = u;
  }
}

// ---------------- MHA2: block per (b,h), softmax over 2049 keys ------------
__global__ LCONST void mha2_kernel(const float* __restrict__ sqp, const float* __restrict__ skp,
                                   const float* __restrict__ svp, const u16* __restrict__ pk,
                                   const u16* __restrict__ pv, float* __restrict__ attn2) {
  __shared__ float lgs[2049];
  __shared__ float rmax[4];
  __shared__ float rsum[4];
  __shared__ float racc[4][32];
  const int bh = blockIdx.x;
  const int b = bh >> 3, h = bh & 7;
  const int tid = threadIdx.x;
  const int lane = tid & 63, wid = tid >> 6;
  const int off = h * 32;
  const float sc = 0.17677669529663687f;

  float qf[32];
  {
    const float* q = sqp + b * 256 + off;
    #pragma unroll
    for (int j = 0; j < 32; j++) qf[j] = q[j];
  }
  float lmax = -1e30f;
  for (int idx = tid; idx < 2049; idx += 256) {
    float d = 0.f;
    if (idx == 0) {
      const float* k = skp + b * 256 + off;
      #pragma unroll
      for (int j = 0; j < 32; j++) d = fmaf(qf[j], k[j], d);
    } else {
      const u16* k = pk + ((size_t)b * 2048 + (idx - 1)) * 256 + off;
      #pragma unroll
      for (int cc = 0; cc < 4; cc++) d += dot8(*(const uint4*)(k + cc * 8), qf + cc * 8);
    }
    d *= sc;
    lgs[idx] = d;
    lmax = fmaxf(lmax, d);
  }
  #pragma unroll
  for (int o = 32; o; o >>= 1) lmax = fmaxf(lmax, __shfl_down(lmax, o));
  if (lane == 0) rmax[wid] = lmax;
  __syncthreads();
  const float M = fmaxf(fmaxf(rmax[0], rmax[1]), fmaxf(rmax[2], rmax[3]));

  float lsum = 0.f;
  float a[32];
  #pragma unroll
  for (int j = 0; j < 32; j++) a[j] = 0.f;
  for (int idx = tid; idx < 2049; idx += 256) {
    float wt = __expf(lgs[idx] - M);
    lsum += wt;
    if (idx == 0) {
      const float* v = svp + b * 256 + off;
      #pragma unroll
      for (int j = 0; j < 32; j++) a[j] = fmaf(wt, v[j], a[j]);
    } else {
      const u16* v = pv + ((size_t)b * 2048 + (idx - 1)) * 256 + off;
      #pragma unroll
      for (int cc = 0; cc < 4; cc++) fma8(*(const uint4*)(v + cc * 8), wt, a + cc * 8);
    }
  }
  #pragma unroll
  for (int o = 32; o; o >>= 1) lsum += __shfl_down(lsum, o);
  if (lane == 0) rsum[wid] = lsum;
  #pragma unroll
  for (int j = 0; j < 32; j++) {
    float v = a[j];
    #pragma unroll
    for (int o = 32; o; o >>= 1) v += __shfl_down(v, o);
    if (lane == 0) racc[wid][j] = v;
  }
  __syncthreads();
  if (tid < 32) {
    float den = rsum[0] + rsum[1] + rsum[2] + rsum[3];
    float o = racc[0][tid] + racc[1][tid] + racc[2][tid] + racc[3][tid];
    attn2[b * 256 + off + tid] = o / den;
  }
}

// ===========================================================================
extern "C" void kernel_launch(void* const* d_in, const int* in_sizes, int n_in,
                              void* d_out, int out_size, void* d_ws, size_t ws_size,
                              hipStream_t stream) {
  const float* e   = (const float*)d_in[0];
  const float* Wq  = (const float*)d_in[1];
  const float* Wk  = (const float*)d_in[2];
  const float* Wv  = (const float*)d_in[3];
  const float* Wo  = (const float*)d_in[4];
  const float* bo  = (const float*)d_in[5];
  const float* W1  = (const float*)d_in[6];
  const float* b1  = (const float*)d_in[7];
  const float* W2  = (const float*)d_in[8];
  const float* b2  = (const float*)d_in[9];
  const float* g1  = (const float*)d_in[10];
  const float* be1 = (const float*)d_in[11];
  const float* g2  = (const float*)d_in[12];
  const float* be2 = (const float*)d_in[13];

  char* wsb = (char*)d_ws;
  size_t off = 0;
  auto alc = [&](size_t n) { void* p = wsb + off; off += (n + 255) & ~(size_t)255; return p; };
  u16* Wqkv_t = (u16*)alc(768 * 256 * 2);     // rows 0-255 Wq, 256-511 Wk, 512-767 Wv
  u16* Wo_t   = (u16*)alc(65536 * 2);
  u16* W1_t   = (u16*)alc(262144 * 2);
  u16* W2_t   = (u16*)alc(262144 * 2);
  float* sA    = (float*)alc(4096 * 4);
  float* sB    = (float*)alc(4096 * 4);
  float* sqp   = (float*)alc(4096 * 4);
  float* skp   = (float*)alc(4096 * 4);
  float* svp   = (float*)alc(4096 * 4);
  float* attn2 = (float*)alc(4096 * 4);
  float* part  = (float*)alc(524288);
  const size_t SZ = 16777216;                 // 32768*256*2 bytes
  u16* hq   = (u16*)alc(SZ);                  // ffn1 aliases hq..pk (64 MB)
  u16* ek   = (u16*)alc(SZ);
  u16* ev   = (u16*)alc(SZ);
  u16* pk   = (u16*)alc(SZ);
  u16* pv   = (u16*)alc(SZ);
  u16* ao   = (u16*)alc(SZ);
  u16* hbuf = (u16*)alc(SZ);
  u16* ebf  = (u16*)alc(SZ);                  // later reused as out1 (bf16)
  u16* ffn1 = hq;
  u16* out1 = ebf;

  const int M = 32768;
  float* outp  = (float*)d_out;
  float* s_out = outp + 8388608;

  // ---- weights -> bf16 transposed ----
  tcast_kernel<<<256, 256, 0, stream>>>(Wq, Wqkv_t, 256, 256);
  tcast_kernel<<<256, 256, 0, stream>>>(Wk, Wqkv_t + 65536, 256, 256);
  tcast_kernel<<<256, 256, 0, stream>>>(Wv, Wqkv_t + 131072, 256, 256);
  tcast_kernel<<<256, 256, 0, stream>>>(Wo, Wo_t, 256, 256);
  tcast_kernel<<<1024, 256, 0, stream>>>(W1, W1_t, 256, 1024);
  tcast_kernel<<<1024, 256, 0, stream>>>(W2, W2_t, 1024, 256);
  // ---- s0 = mean_L(e); e -> bf16 ----
  mean_part_kernel<<<512, 256, 0, stream>>>(e, part, ebf);
  mean_fin_kernel<<<16, 256, 0, stream>>>(part, sA);

  // ---------------- cycle 1 (h = e, s = sA) ----------------
  sgemm3_kernel<<<dim3(16, 3), 256, 0, stream>>>(sA, Wq, Wk, Wv, sqp, skp, svp);
  gemm2_kernel<128, 0><<<1536, 256, 0, stream>>>(ebf, Wqkv_t, nullptr, hq, ek, ev,
      nullptr, nullptr, nullptr, nullptr, nullptr, M, 768, 256);
  attn1_kernel<<<1024, 256, 0, stream>>>(hq, ek, ev, ek, ev, skp, svp, ao);
  gemm2_kernel<256, 1><<<256, 512, 0, stream>>>(ao, Wo_t, bo, hbuf, nullptr, nullptr,
      nullptr, nullptr, nullptr, nullptr, nullptr, M, 256, 256);
  gemm2_kernel<128, 0><<<1536, 256, 0, stream>>>(hbuf, Wqkv_t, nullptr, hq, pk, pv,
      nullptr, nullptr, nullptr, nullptr, nullptr, M, 768, 256);  // hq2, pk, pv
  mha2_kernel<<<128, 256, 0, stream>>>(sqp, skp, svp, pk, pv, attn2);
  sgemm_kernel<true, true><<<16, 256, 0, stream>>>(attn2, Wo, bo, sB);

  // ---------------- cycle 2 (h = hbuf, s = sB) ----------------
  sgemm3_kernel<<<dim3(16, 3), 256, 0, stream>>>(sB, Wq, Wk, Wv, sqp, skp, svp);
  attn1_kernel<<<1024, 256, 0, stream>>>(hq, pk, pv, ek, ev, skp, svp, ao);
  gemm2_kernel<256, 2><<<256, 512, 0, stream>>>(ao, Wo_t, bo, hbuf, out1, nullptr,
      e, nullptr, g1, be1, nullptr, M, 256, 256);                 // h2 + fused LN1
  gemm2_kernel<128, 0><<<1024, 256, 0, stream>>>(hbuf, Wqkv_t + 65536, nullptr, pk, pv, nullptr,
      nullptr, nullptr, nullptr, nullptr, nullptr, M, 512, 256);  // pk2, pv2
  mha2_kernel<<<128, 256, 0, stream>>>(sqp, skp, svp, pk, pv, attn2);
  sgemm_kernel<true, true><<<16, 256, 0, stream>>>(attn2, Wo, bo, s_out);

  // ---------------- epilogue: FFN (LN1/LN2 fused into GEMMs) ----------------
  gemm2_kernel<128, 1><<<2048, 256, 0, stream>>>(out1, W1_t, b1, ffn1, nullptr, nullptr,
      nullptr, nullptr, nullptr, nullptr, nullptr, M, 1024, 256);
  gemm2_kernel<256, 4><<<256, 512, 0, stream>>>(ffn1, W2_t, b2, nullptr, nullptr, nullptr,
      nullptr, out1, g2, be2, outp, M, 256, 1024);
  (void)in_sizes; (void)n_in; (void)out_size; (void)ws_size;
}

// Round 3
// 338.464 us; speedup vs baseline: 1.4910x; 1.0854x over previous
//
#include <hip/hip_runtime.h>

typedef unsigned short u16;
typedef unsigned int u32;
typedef __attribute__((ext_vector_type(8))) short bf16x8;
typedef __attribute__((ext_vector_type(4))) float f32x4;

#define LCONST __launch_bounds__(256)

__device__ __forceinline__ u16 f2bf(float f) {
  u32 u = __float_as_uint(f);
  u32 r = (u + 0x7FFFu + ((u >> 16) & 1u)) >> 16;
  return (u16)r;
}
__device__ __forceinline__ float bflo(u32 w) { return __uint_as_float(w << 16); }
__device__ __forceinline__ float bfhi(u32 w) { return __uint_as_float(w & 0xFFFF0000u); }
__device__ __forceinline__ float b2f(u16 v) { return __uint_as_float(((u32)v) << 16); }

__device__ __forceinline__ float dot8(uint4 u, const float* q) {
  return q[0]*bflo(u.x) + q[1]*bfhi(u.x) + q[2]*bflo(u.y) + q[3]*bfhi(u.y)
       + q[4]*bflo(u.z) + q[5]*bfhi(u.z) + q[6]*bflo(u.w) + q[7]*bfhi(u.w);
}
__device__ __forceinline__ void fma8(uint4 u, float wt, float* a) {
  a[0] = fmaf(wt, bflo(u.x), a[0]); a[1] = fmaf(wt, bfhi(u.x), a[1]);
  a[2] = fmaf(wt, bflo(u.y), a[2]); a[3] = fmaf(wt, bfhi(u.y), a[3]);
  a[4] = fmaf(wt, bflo(u.z), a[4]); a[5] = fmaf(wt, bfhi(u.z), a[5]);
  a[6] = fmaf(wt, bflo(u.w), a[6]); a[7] = fmaf(wt, bfhi(u.w), a[7]);
}

// async global -> LDS, 16 bytes per lane. LDS dest = wave-uniform base + lane*16.
__device__ __forceinline__ void gload16(const u16* g, u16* l) {
  __builtin_amdgcn_global_load_lds(
      (const __attribute__((address_space(1))) unsigned int*)g,
      (__attribute__((address_space(3))) unsigned int*)l, 16, 0, 0);
}

// ---------------- all weight transpose-casts in ONE launch -----------------
__global__ LCONST void wcast_kernel(const float* __restrict__ Wq, const float* __restrict__ Wk,
                                    const float* __restrict__ Wv, const float* __restrict__ Wo,
                                    const float* __restrict__ W1, const float* __restrict__ W2,
                                    u16* __restrict__ Wqkv_t, u16* __restrict__ Wo_t,
                                    u16* __restrict__ W1_t, u16* __restrict__ W2_t) {
  int idx = blockIdx.x * 256 + threadIdx.x;       // 786432 total
  if (idx < 196608) {                             // Wq|Wk|Wv (256x256 each)
    int sub = idx >> 16, r = idx & 65535;
    int n = r >> 8, k = r & 255;
    const float* src = (sub == 0) ? Wq : ((sub == 1) ? Wk : Wv);
    Wqkv_t[idx] = f2bf(src[(size_t)k * 256 + n]);
  } else if (idx < 262144) {                      // Wo (256x256)
    int r = idx - 196608;
    int n = r >> 8, k = r & 255;
    Wo_t[r] = f2bf(Wo[(size_t)k * 256 + n]);
  } else if (idx < 524288) {                      // W1 (256x1024) -> [1024][256]
    int r = idx - 262144;
    int n = r >> 8, k = r & 255;
    W1_t[r] = f2bf(W1[(size_t)k * 1024 + n]);
  } else {                                        // W2 (1024x256) -> [256][1024]
    int r = idx - 524288;
    int n = r >> 10, k = r & 1023;
    W2_t[r] = f2bf(W2[(size_t)k * 256 + n]);
  }
}

// ---------------- mean over L (also casts e -> bf16) -----------------------
__global__ LCONST void mean_part_kernel(const float* __restrict__ e, float* __restrict__ part,
                                        u16* __restrict__ ebf) {
  int blk = blockIdx.x;            // b*32 + c
  int b = blk >> 5, c = blk & 31;
  int d = threadIdx.x;
  size_t base = ((size_t)b * 2048 + (size_t)c * 64) * 256 + d;
  float s = 0.f;
  #pragma unroll 8
  for (int i = 0; i < 64; i++) {
    float v = e[base + (size_t)i * 256];
    s += v;
    ebf[base + (size_t)i * 256] = f2bf(v);
  }
  part[(size_t)blk * 256 + d] = s;
}

// ---------------- MFMA GEMM: C = A(MxK,bf16) * Bt(NxK,bf16)^T --------------
// (BM,BN) = (128,128): 256 thr, 2x2 waves, wave=64x64.
// (BM,BN) = (64,256):  512 thr, 2x4 waves, wave=32x64.
// EPI: 0 = plain bf16 store routed into 256-wide buffers C0/C1/C2 by col>>8
//      1 = relu(acc+bias) -> bf16 C0 (stride N)
//      2 = Wo+LN1: h=relu(acc+bias)->C0; out1=LN(resbf+h)->C1 (bf16)
//      4 = FFN2+LN2: x=acc+bias+resbf; LN(x) -> Fout (f32)
template <int BM, int BN, int EPI>
__global__ __launch_bounds__((BM == 128) ? 256 : 512)
void gemm3_kernel(const u16* __restrict__ A, const u16* __restrict__ Bt,
                  const float* __restrict__ bias,
                  u16* __restrict__ C0, u16* __restrict__ C1, u16* __restrict__ C2,
                  const u16* __restrict__ resbf,
                  const float* __restrict__ g, const float* __restrict__ be,
                  float* __restrict__ Fout,
                  int M, int N, int K) {
  constexpr int NT = (BM == 128) ? 256 : 512;
  constexpr int WAVES = NT / 64;
  constexpr int WNW = (BN == 256) ? 4 : 2;   // waves along N
  constexpr int WMW = WAVES / WNW;           // waves along M
  constexpr int WR = BM / WMW;               // rows per wave (64 or 32)
  constexpr int MR = WR / 16;                // 4 or 2
  constexpr int ACH_PW = (BM / 8) / WAVES;   // A 1KB chunks per wave
  constexpr int BCH_PW = (BN / 8) / WAVES;
  __shared__ __align__(16) u16 As[BM * 64];
  __shared__ __align__(16) u16 Bs[BN * 64];

  const int tid = threadIdx.x, lane = tid & 63, wid = tid >> 6;
  const int wm = wid / WNW, wn = wid % WNW;

  // XCD-chunked swizzle (grids always %8==0), row-major (mb,nb)
  const int ncol = N / BN;
  const int nwg = gridDim.x;
  const int bid = blockIdx.x;
  const int swz = (bid & 7) * (nwg >> 3) + (bid >> 3);
  const int mb = swz / ncol, nb = swz - mb * ncol;
  const int m0 = mb * BM, n0 = nb * BN;

  const int lrow8 = lane >> 3;               // row within 8-row chunk
  const int cg = (lane & 7) ^ lrow8;         // pre-swizzled global 16B-slot

  f32x4 acc[MR][4] = {};
  for (int kt = 0; kt < K; kt += 64) {
    #pragma unroll
    for (int it = 0; it < ACH_PW; it++) {
      int ca = wid * ACH_PW + it;
      int row = ca * 8 + lrow8;
      gload16(A + (size_t)(m0 + row) * K + kt + cg * 8, (u16*)As + ca * 512);
    }
    #pragma unroll
    for (int it = 0; it < BCH_PW; it++) {
      int cb = wid * BCH_PW + it;
      int row = cb * 8 + lrow8;
      gload16(Bt + (size_t)(n0 + row) * K + kt + cg * 8, (u16*)Bs + cb * 512);
    }
    __syncthreads();
    const int lr = lane & 15, hi = lane >> 4;
    #pragma unroll
    for (int kk = 0; kk < 2; kk++) {
      const int slot = (kk * 4 + hi) ^ (lr & 7);
      bf16x8 af[MR], bfr[4];
      #pragma unroll
      for (int m = 0; m < MR; m++)
        af[m] = *(const bf16x8*)&As[(wm * WR + m * 16 + lr) * 64 + slot * 8];
      #pragma unroll
      for (int n = 0; n < 4; n++)
        bfr[n] = *(const bf16x8*)&Bs[(wn * 64 + n * 16 + lr) * 64 + slot * 8];
      #pragma unroll
      for (int m = 0; m < MR; m++)
        #pragma unroll
        for (int n = 0; n < 4; n++)
          acc[m][n] = __builtin_amdgcn_mfma_f32_16x16x32_bf16(af[m], bfr[n], acc[m][n], 0, 0, 0);
    }
    __syncthreads();
  }

  const int lr = lane & 15, hi = lane >> 4;
  if constexpr (EPI == 0) {
    const int bsel = n0 >> 8;
    u16* C = (bsel == 0) ? C0 : ((bsel == 1) ? C1 : C2);
    const int nbase = n0 & 255;
    #pragma unroll
    for (int m = 0; m < MR; m++)
      #pragma unroll
      for (int n = 0; n < 4; n++)
        #pragma unroll
        for (int r = 0; r < 4; r++) {
          int row = m0 + wm * WR + m * 16 + hi * 4 + r;
          int col = nbase + wn * 64 + n * 16 + lr;
          C[(size_t)row * 256 + col] = f2bf(acc[m][n][r]);
        }
  } else if constexpr (EPI == 1) {
    #pragma unroll
    for (int m = 0; m < MR; m++)
      #pragma unroll
      for (int n = 0; n < 4; n++)
        #pragma unroll
        for (int r = 0; r < 4; r++) {
          int row = m0 + wm * WR + m * 16 + hi * 4 + r;
          int col = n0 + wn * 64 + n * 16 + lr;
          float v = fmaxf(acc[m][n][r] + bias[col], 0.f);
          C0[(size_t)row * N + col] = f2bf(v);
        }
  } else {  // EPI 2 / 4: full-row (BN=256) LN epilogues
    __shared__ float rsum[BM], rsq[BM];
    if (tid < BM) { rsum[tid] = 0.f; rsq[tid] = 0.f; }
    __syncthreads();
    #pragma unroll
    for (int m = 0; m < MR; m++)
      #pragma unroll
      for (int n = 0; n < 4; n++)
        #pragma unroll
        for (int r = 0; r < 4; r++) {
          int rl = wm * WR + m * 16 + hi * 4 + r;
          int col = wn * 64 + n * 16 + lr;
          size_t gi = (size_t)(m0 + rl) * 256 + col;
          float v = acc[m][n][r] + bias[col];
          float x;
          if constexpr (EPI == 2) {
            v = fmaxf(v, 0.f);
            C0[gi] = f2bf(v);            // h2
            x = b2f(resbf[gi]) + v;      // e + h
          } else {
            x = b2f(resbf[gi]) + v;      // out1 + ffn
          }
          acc[m][n][r] = x;
        }
    #pragma unroll
    for (int m = 0; m < MR; m++)
      #pragma unroll
      for (int r = 0; r < 4; r++) {
        float s = 0.f, q = 0.f;
        #pragma unroll
        for (int n = 0; n < 4; n++) { float x = acc[m][n][r]; s += x; q += x * x; }
        #pragma unroll
        for (int off = 1; off < 16; off <<= 1) {
          s += __shfl_xor(s, off);
          q += __shfl_xor(q, off);
        }
        if (lr == 0) {
          int rl = wm * WR + m * 16 + hi * 4 + r;
          atomicAdd(&rsum[rl], s);
          atomicAdd(&rsq[rl], q);
        }
      }
    __syncthreads();
    #pragma unroll
    for (int m = 0; m < MR; m++)
      #pragma unroll
      for (int n = 0; n < 4; n++)
        #pragma unroll
        for (int r = 0; r < 4; r++) {
          int rl = wm * WR + m * 16 + hi * 4 + r;
          int col = wn * 64 + n * 16 + lr;
          size_t gi = (size_t)(m0 + rl) * 256 + col;
          float mu = rsum[rl] * (1.f / 256.f);
          float var = rsq[rl] * (1.f / 256.f) - mu * mu;
          float rstd = rsqrtf(fmaxf(var, 0.f) + 1e-6f);
          float o = g[col] * (acc[m][n][r] - mu) * rstd + be[col];
          if constexpr (EPI == 2) C1[gi] = f2bf(o);   // out1 bf16
          else                    Fout[gi] = o;       // out2 f32
        }
  }
}

// ---------------- small f32 GEMMs for s-vectors (opt. fused mean) ----------
__global__ LCONST void sgemm3_kernel(const float* __restrict__ X, const float* __restrict__ part,
                                     const float* __restrict__ Wq, const float* __restrict__ Wk,
                                     const float* __restrict__ Wv, float* __restrict__ Yq,
                                     float* __restrict__ Yk, float* __restrict__ Yv) {
  __shared__ float xs[256];
  int b = blockIdx.x, sel = blockIdx.y, tid = threadIdx.x;
  if (part) {
    float s = 0.f;
    #pragma unroll
    for (int c = 0; c < 32; c++) s += part[((size_t)b * 32 + c) * 256 + tid];
    xs[tid] = s * (1.f / 2048.f);
  } else {
    xs[tid] = X[b * 256 + tid];
  }
  __syncthreads();
  const float* W = (sel == 0) ? Wq : ((sel == 1) ? Wk : Wv);
  float* Y = (sel == 0) ? Yq : ((sel == 1) ? Yk : Yv);
  float acc = 0.f;
  #pragma unroll 4
  for (int d = 0; d < 256; d++) acc = fmaf(xs[d], W[(size_t)d * 256 + tid], acc);
  Y[b * 256 + tid] = acc;
}

template <bool RELU, bool BIAS>
__global__ LCONST void sgemm_kernel(const float* __restrict__ X, const float* __restrict__ W,
                                    const float* __restrict__ bias, float* __restrict__ Y) {
  int b = blockIdx.x, tid = threadIdx.x;
  const float* xr = X + b * 256;
  float acc = 0.f;
  #pragma unroll 4
  for (int d = 0; d < 256; d++) acc = fmaf(xr[d], W[(size_t)d * 256 + tid], acc);
  if constexpr (BIAS) acc += bias[tid];
  if constexpr (RELU) acc = fmaxf(acc, 0.f);
  Y[b * 256 + tid] = acc;
}

// ---------------- fused 5-key per-token attention (MHA1 core) --------------
__global__ LCONST void attn1_kernel(const u16* __restrict__ hq, const u16* __restrict__ pk,
                                    const u16* __restrict__ pv, const u16* __restrict__ ek,
                                    const u16* __restrict__ ev, const float* __restrict__ skp,
                                    const float* __restrict__ svp, u16* __restrict__ outp) {
  int t = blockIdx.x * 256 + threadIdx.x;     // B*L*H threads
  int h = t & 7;
  size_t token = (size_t)(t >> 3);
  int b = (int)(token >> 11);
  int i = (int)(token & 2047);
  size_t tb = (size_t)b << 11;
  size_t ip = tb + ((i + 1) & 2047);
  size_t im = tb + ((i + 2047) & 2047);
  const int off = h * 32;

  float qf[32];
  {
    const u16* q = hq + token * 256 + off;
    #pragma unroll
    for (int c = 0; c < 4; c++) {
      uint4 u = *(const uint4*)(q + c * 8);
      qf[c*8+0] = bflo(u.x); qf[c*8+1] = bfhi(u.x);
      qf[c*8+2] = bflo(u.y); qf[c*8+3] = bfhi(u.y);
      qf[c*8+4] = bflo(u.z); qf[c*8+5] = bfhi(u.z);
      qf[c*8+6] = bflo(u.w); qf[c*8+7] = bfhi(u.w);
    }
  }
  const u16* kr0 = pk + ip * 256 + off;
  const u16* kr1 = pk + token * 256 + off;
  const u16* kr2 = pk + im * 256 + off;
  const u16* kr3 = ek + token * 256 + off;
  float lg[5];
  {
    float d0 = 0, d1 = 0, d2 = 0, d3 = 0;
    #pragma unroll
    for (int cc = 0; cc < 4; cc++) {
      d0 += dot8(*(const uint4*)(kr0 + cc * 8), qf + cc * 8);
      d1 += dot8(*(const uint4*)(kr1 + cc * 8), qf + cc * 8);
      d2 += dot8(*(const uint4*)(kr2 + cc * 8), qf + cc * 8);
      d3 += dot8(*(const uint4*)(kr3 + cc * 8), qf + cc * 8);
    }
    lg[0] = d0; lg[1] = d1; lg[2] = d2; lg[3] = d3;
    float d4 = 0;
    const float* s = skp + b * 256 + off;
    #pragma unroll
    for (int j = 0; j < 32; j++) d4 = fmaf(qf[j], s[j], d4);
    lg[4] = d4;
  }
  const float sc = 0.17677669529663687f;      // 1/sqrt(32)
  float m = lg[0];
  #pragma unroll
  for (int c = 1; c < 5; c++) m = fmaxf(m, lg[c]);
  float w[5], den = 0.f;
  #pragma unroll
  for (int c = 0; c < 5; c++) { w[c] = __expf((lg[c] - m) * sc); den += w[c]; }

  float a[32];
  #pragma unroll
  for (int j = 0; j < 32; j++) a[j] = 0.f;
  const u16* vr0 = pv + ip * 256 + off;
  const u16* vr1 = pv + token * 256 + off;
  const u16* vr2 = pv + im * 256 + off;
  const u16* vr3 = ev + token * 256 + off;
  #pragma unroll
  for (int cc = 0; cc < 4; cc++) {
    fma8(*(const uint4*)(vr0 + cc * 8), w[0], a + cc * 8);
    fma8(*(const uint4*)(vr1 + cc * 8), w[1], a + cc * 8);
    fma8(*(const uint4*)(vr2 + cc * 8), w[2], a + cc * 8);
    fma8(*(const uint4*)(vr3 + cc * 8), w[3], a + cc * 8);
  }
  {
    const float* s = svp + b * 256 + off;
    #pragma unroll
    for (int j = 0; j < 32; j++) a[j] = fmaf(w[4], s[j], a[j]);
  }
  float inv = 1.f / den;
  u16* o = outp + token * 256 + off;
  #pragma unroll
  for (int c = 0; c < 4; c++) {
    uint4 u;
    u.x = (u32)f2bf(a[c*8+0] * inv) | ((u32)f2bf(a[c*8+1] * inv) << 16);
    u.y = (u32)f2bf(a[c*8+2] * inv) | ((u32)f2bf(a[c*8+3] * inv) << 16);
    u.z = (u32)f2bf(a[c*8+4] * inv) | ((u32)f2bf(a[c*8+5] * inv) << 16);
    u.w = (u32)f2bf(a[c*8+6] * inv) | ((u32)f2bf(a[c*8+7] * inv) << 16);
    *(uint4*)(o + c * 8) = u;
  }
}

// ---------------- MHA2 split: 4 key-chunks per (b,h) -----------------------
// partial[blk*36]: [0]=m, [1]=l, [2..33]=acc
__global__ LCONST void mha2a_kernel(const float* __restrict__ sqp, const float* __restrict__ skp,
                                    const float* __restrict__ svp, const u16* __restrict__ pk,
                                    const u16* __restrict__ pv, float* __restrict__ partial) {
  __shared__ float rmax[4], rsum[4], racc[4][32];
  const int blk = blockIdx.x;                 // bh*4 + c
  const int bh = blk >> 2, c = blk & 3;
  const int b = bh >> 3, h = bh & 7;
  const int tid = threadIdx.x;
  const int lane = tid & 63, wid = tid >> 6;
  const int off = h * 32;
  const float sc = 0.17677669529663687f;

  float qf[32];
  {
    const float* q = sqp + b * 256 + off;
    #pragma unroll
    for (int j = 0; j < 32; j++) qf[j] = q[j];
  }
  const int k0 = c * 512 + tid;               // two h-keys per thread
  const int k1 = k0 + 256;
  const u16* kp0 = pk + ((size_t)b * 2048 + k0) * 256 + off;
  const u16* kp1 = pk + ((size_t)b * 2048 + k1) * 256 + off;
  float d0 = 0.f, d1 = 0.f;
  #pragma unroll
  for (int cc = 0; cc < 4; cc++) {
    d0 += dot8(*(const uint4*)(kp0 + cc * 8), qf + cc * 8);
    d1 += dot8(*(const uint4*)(kp1 + cc * 8), qf + cc * 8);
  }
  d0 *= sc; d1 *= sc;
  float ds = -1e30f;
  if (c == 0 && tid == 0) {                   // the s-key
    float d = 0.f;
    const float* k = skp + b * 256 + off;
    #pragma unroll
    for (int j = 0; j < 32; j++) d = fmaf(qf[j], k[j], d);
    ds = d * sc;
  }
  float lmax = fmaxf(fmaxf(d0, d1), ds);
  #pragma unroll
  for (int o = 32; o; o >>= 1) lmax = fmaxf(lmax, __shfl_down(lmax, o));
  if (lane == 0) rmax[wid] = lmax;
  __syncthreads();
  const float M = fmaxf(fmaxf(rmax[0], rmax[1]), fmaxf(rmax[2], rmax[3]));

  float w0 = __expf(d0 - M), w1 = __expf(d1 - M);
  float lsum = w0 + w1;
  float a[32];
  #pragma unroll
  for (int j = 0; j < 32; j++) a[j] = 0.f;
  const u16* vp0 = pv + ((size_t)b * 2048 + k0) * 256 + off;
  const u16* vp1 = pv + ((size_t)b * 2048 + k1) * 256 + off;
  #pragma unroll
  for (int cc = 0; cc < 4; cc++) {
    fma8(*(const uint4*)(vp0 + cc * 8), w0, a + cc * 8);
    fma8(*(const uint4*)(vp1 + cc * 8), w1, a + cc * 8);
  }
  if (c == 0 && tid == 0) {
    float ws = __expf(ds - M);
    lsum += ws;
    const float* v = svp + b * 256 + off;
    #pragma unroll
    for (int j = 0; j < 32; j++) a[j] = fmaf(ws, v[j], a[j]);
  }
  #pragma unroll
  for (int o = 32; o; o >>= 1) lsum += __shfl_down(lsum, o);
  if (lane == 0) rsum[wid] = lsum;
  #pragma unroll
  for (int j = 0; j < 32; j++) {
    float v = a[j];
    #pragma unroll
    for (int o = 32; o; o >>= 1) v += __shfl_down(v, o);
    if (lane == 0) racc[wid][j] = v;
  }
  __syncthreads();
  float* P = partial + (size_t)blk * 36;
  if (tid < 32) {
    P[2 + tid] = racc[0][tid] + racc[1][tid] + racc[2][tid] + racc[3][tid];
    if (tid == 0) {
      P[0] = M;
      P[1] = rsum[0] + rsum[1] + rsum[2] + rsum[3];
    }
  }
}

__global__ __launch_bounds__(256) void mha2b_kernel(const float* __restrict__ partial,
                                                    float* __restrict__ attn2) {
  int gtid = blockIdx.x * 256 + threadIdx.x;  // 4096 = 128 bh * 32 d
  int bh = gtid >> 5, d = gtid & 31;
  int b = bh >> 3, h = bh & 7;
  const float* P = partial + (size_t)bh * 4 * 36;
  float M = fmaxf(fmaxf(P[0], P[36]), fmaxf(P[72], P[108]));
  float l = 0.f, o = 0.f;
  #pragma unroll
  for (int c = 0; c < 4; c++) {
    float f = __expf(P[c * 36] - M);
    l += f * P[c * 36 + 1];
    o += f * P[c * 36 + 2 + d];
  }
  attn2[b * 256 + h * 32 + d] = o / l;
}

// ===========================================================================
extern "C" void kernel_launch(void* const* d_in, const int* in_sizes, int n_in,
                              void* d_out, int out_size, void* d_ws, size_t ws_size,
                              hipStream_t stream) {
  const float* e   = (const float*)d_in[0];
  const float* Wq  = (const float*)d_in[1];
  const float* Wk  = (const float*)d_in[2];
  const float* Wv  = (const float*)d_in[3];
  const float* Wo  = (const float*)d_in[4];
  const float* bo  = (const float*)d_in[5];
  const float* W1  = (const float*)d_in[6];
  const float* b1  = (const float*)d_in[7];
  const float* W2  = (const float*)d_in[8];
  const float* b2  = (const float*)d_in[9];
  const float* g1  = (const float*)d_in[10];
  const float* be1 = (const float*)d_in[11];
  const float* g2  = (const float*)d_in[12];
  const float* be2 = (const float*)d_in[13];

  char* wsb = (char*)d_ws;
  size_t off = 0;
  auto alc = [&](size_t n) { void* p = wsb + off; off += (n + 255) & ~(size_t)255; return p; };
  u16* Wqkv_t = (u16*)alc(768 * 256 * 2);     // rows 0-255 Wq, 256-511 Wk, 512-767 Wv
  u16* Wo_t   = (u16*)alc(65536 * 2);
  u16* W1_t   = (u16*)alc(262144 * 2);
  u16* W2_t   = (u16*)alc(262144 * 2);
  float* sB    = (float*)alc(4096 * 4);
  float* sqp   = (float*)alc(4096 * 4);
  float* skp   = (float*)alc(4096 * 4);
  float* svp   = (float*)alc(4096 * 4);
  float* attn2 = (float*)alc(4096 * 4);
  float* partM = (float*)alc(512 * 36 * 4);
  float* part  = (float*)alc(524288);
  const size_t SZ = 16777216;                 // 32768*256*2 bytes
  u16* hq   = (u16*)alc(SZ);                  // ffn1 aliases hq..pk (64 MB)
  u16* ek   = (u16*)alc(SZ);
  u16* ev   = (u16*)alc(SZ);
  u16* pk   = (u16*)alc(SZ);
  u16* pv   = (u16*)alc(SZ);
  u16* ao   = (u16*)alc(SZ);
  u16* hbuf = (u16*)alc(SZ);
  u16* ebf  = (u16*)alc(SZ);
  u16* out1 = (u16*)alc(SZ);
  u16* ffn1 = hq;

  const int M = 32768;
  float* outp  = (float*)d_out;
  float* s_out = outp + 8388608;

  // ---- all weights -> bf16 transposed (one launch) ----
  wcast_kernel<<<3072, 256, 0, stream>>>(Wq, Wk, Wv, Wo, W1, W2, Wqkv_t, Wo_t, W1_t, W2_t);
  // ---- partial mean; e -> bf16 ----
  mean_part_kernel<<<512, 256, 0, stream>>>(e, part, ebf);

  // ---------------- cycle 1 (h = e, s = s0) ----------------
  sgemm3_kernel<<<dim3(16, 3), 256, 0, stream>>>(nullptr, part, Wq, Wk, Wv, sqp, skp, svp);
  gemm3_kernel<128, 128, 0><<<1536, 256, 0, stream>>>(ebf, Wqkv_t, nullptr, hq, ek, ev,
      nullptr, nullptr, nullptr, nullptr, M, 768, 256);
  attn1_kernel<<<1024, 256, 0, stream>>>(hq, ek, ev, ek, ev, skp, svp, ao);
  gemm3_kernel<64, 256, 1><<<512, 512, 0, stream>>>(ao, Wo_t, bo, hbuf, nullptr, nullptr,
      nullptr, nullptr, nullptr, nullptr, M, 256, 256);
  gemm3_kernel<128, 128, 0><<<1536, 256, 0, stream>>>(hbuf, Wqkv_t, nullptr, hq, pk, pv,
      nullptr, nullptr, nullptr, nullptr, M, 768, 256);   // hq2, pk, pv
  mha2a_kernel<<<512, 256, 0, stream>>>(sqp, skp, svp, pk, pv, partM);
  mha2b_kernel<<<16, 256, 0, stream>>>(partM, attn2);
  sgemm_kernel<true, true><<<16, 256, 0, stream>>>(attn2, Wo, bo, sB);

  // ---------------- cycle 2 (h = h1, s = s1) ----------------
  sgemm3_kernel<<<dim3(16, 3), 256, 0, stream>>>(sB, nullptr, Wq, Wk, Wv, sqp, skp, svp);
  attn1_kernel<<<1024, 256, 0, stream>>>(hq, pk, pv, ek, ev, skp, svp, ao);
  gemm3_kernel<64, 256, 2><<<512, 512, 0, stream>>>(ao, Wo_t, bo, hbuf, out1, nullptr,
      ebf, g1, be1, nullptr, M, 256, 256);                // h2 + fused LN1
  gemm3_kernel<128, 128, 0><<<1024, 256, 0, stream>>>(hbuf, Wqkv_t + 65536, nullptr, pk, pv, nullptr,
      nullptr, nullptr, nullptr, nullptr, M, 512, 256);   // pk2, pv2
  mha2a_kernel<<<512, 256, 0, stream>>>(sqp, skp, svp, pk, pv, partM);
  mha2b_kernel<<<16, 256, 0, stream>>>(partM, attn2);
  sgemm_kernel<true, true><<<16, 256, 0, stream>>>(attn2, Wo, bo, s_out);

  // ---------------- epilogue: FFN (LN1/LN2 fused into GEMMs) ----------------
  gemm3_kernel<128, 128, 1><<<2048, 256, 0, stream>>>(out1, W1_t, b1, ffn1, nullptr, nullptr,
      nullptr, nullptr, nullptr, nullptr, M, 1024, 256);
  gemm3_kernel<64, 256, 4><<<512, 512, 0, stream>>>(ffn1, W2_t, b2, nullptr, nullptr, nullptr,
      out1, g2, be2, outp, M, 256, 1024);
  (void)in_sizes; (void)n_in; (void)out_size; (void)ws_size;
}

// Round 4
// 332.901 us; speedup vs baseline: 1.5159x; 1.0167x over previous
//
#include <hip/hip_runtime.h>

typedef unsigned short u16;
typedef unsigned int u32;
typedef __attribute__((ext_vector_type(8))) short bf16x8;
typedef __attribute__((ext_vector_type(4))) float f32x4;

#define LCONST __launch_bounds__(256)

__device__ __forceinline__ u16 f2bf(float f) {
  u32 u = __float_as_uint(f);
  u32 r = (u + 0x7FFFu + ((u >> 16) & 1u)) >> 16;
  return (u16)r;
}
__device__ __forceinline__ float bflo(u32 w) { return __uint_as_float(w << 16); }
__device__ __forceinline__ float bfhi(u32 w) { return __uint_as_float(w & 0xFFFF0000u); }
__device__ __forceinline__ float b2f(u16 v) { return __uint_as_float(((u32)v) << 16); }

__device__ __forceinline__ float dot8(uint4 u, const float* q) {
  return q[0]*bflo(u.x) + q[1]*bfhi(u.x) + q[2]*bflo(u.y) + q[3]*bfhi(u.y)
       + q[4]*bflo(u.z) + q[5]*bfhi(u.z) + q[6]*bflo(u.w) + q[7]*bfhi(u.w);
}
__device__ __forceinline__ void fma8(uint4 u, float wt, float* a) {
  a[0] = fmaf(wt, bflo(u.x), a[0]); a[1] = fmaf(wt, bfhi(u.x), a[1]);
  a[2] = fmaf(wt, bflo(u.y), a[2]); a[3] = fmaf(wt, bfhi(u.y), a[3]);
  a[4] = fmaf(wt, bflo(u.z), a[4]); a[5] = fmaf(wt, bfhi(u.z), a[5]);
  a[6] = fmaf(wt, bflo(u.w), a[6]); a[7] = fmaf(wt, bfhi(u.w), a[7]);
}

// async global -> LDS, 16 bytes per lane. LDS dest = wave-uniform base + lane*16.
__device__ __forceinline__ void gload16(const u16* g, u16* l) {
  __builtin_amdgcn_global_load_lds(
      (const __attribute__((address_space(1))) unsigned int*)g,
      (__attribute__((address_space(3))) unsigned int*)l, 16, 0, 0);
}

// ---------------- prep: all weight transpose-casts + e-mean (one launch) ---
__global__ LCONST void prep_kernel(const float* __restrict__ e,
                                   const float* __restrict__ Wq, const float* __restrict__ Wk,
                                   const float* __restrict__ Wv, const float* __restrict__ Wo,
                                   const float* __restrict__ W1, const float* __restrict__ W2,
                                   u16* __restrict__ Wqkv_t, u16* __restrict__ Wo_t,
                                   u16* __restrict__ W1_t, u16* __restrict__ W2_t,
                                   float* __restrict__ part, u16* __restrict__ ebf) {
  int blk = blockIdx.x;
  int tid = threadIdx.x;
  if (blk < 3072) {                               // weight transpose-casts
    int idx = blk * 256 + tid;                    // 786432 total
    if (idx < 196608) {                           // Wq|Wk|Wv (256x256 each)
      int sub = idx >> 16, r = idx & 65535;
      int n = r >> 8, k = r & 255;
      const float* src = (sub == 0) ? Wq : ((sub == 1) ? Wk : Wv);
      Wqkv_t[idx] = f2bf(src[(size_t)k * 256 + n]);
    } else if (idx < 262144) {                    // Wo (256x256)
      int r = idx - 196608;
      int n = r >> 8, k = r & 255;
      Wo_t[r] = f2bf(Wo[(size_t)k * 256 + n]);
    } else if (idx < 524288) {                    // W1 (256x1024) -> [1024][256]
      int r = idx - 262144;
      int n = r >> 8, k = r & 255;
      W1_t[r] = f2bf(W1[(size_t)k * 1024 + n]);
    } else {                                      // W2 (1024x256) -> [256][1024]
      int r = idx - 524288;
      int n = r >> 10, k = r & 1023;
      W2_t[r] = f2bf(W2[(size_t)k * 256 + n]);
    }
  } else {                                        // partial mean + e->bf16
    int mb = blk - 3072;                          // 512 blocks
    int b = mb >> 5, c = mb & 31;
    size_t base = ((size_t)b * 2048 + (size_t)c * 64) * 256 + tid;
    float s = 0.f;
    #pragma unroll 8
    for (int i = 0; i < 64; i++) {
      float v = e[base + (size_t)i * 256];
      s += v;
      ebf[base + (size_t)i * 256] = f2bf(v);
    }
    part[(size_t)mb * 256 + tid] = s;
  }
}

// ---------------- MFMA GEMM: C = A(MxK,bf16) * Bt(NxK,bf16)^T --------------
// 512 threads, 2x4 waves. (BM,BN)=(128,256): wave 64x64, MR=4.
//                          (BM,BN)=(64,256):  wave 32x64, MR=2.
// EPI: 0 = plain bf16 store routed into 256-wide buffers C0/C1/C2 by col>>8
//      1 = relu(acc+bias) -> bf16 C0 (stride N)
//      2 = Wo+LN1: h=relu(acc+bias)->C0; out1=LN(resbf+h)->C1 (bf16)
//      4 = FFN2+LN2: x=acc+bias+resbf; LN(x) -> Fout (f32)
template <int BM, int BN, int EPI>
__global__ __launch_bounds__(512, (BM == 128) ? 4 : 6)
void gemm3_kernel(const u16* __restrict__ A, const u16* __restrict__ Bt,
                  const float* __restrict__ bias,
                  u16* __restrict__ C0, u16* __restrict__ C1, u16* __restrict__ C2,
                  const u16* __restrict__ resbf,
                  const float* __restrict__ g, const float* __restrict__ be,
                  float* __restrict__ Fout,
                  int M, int N, int K) {
  constexpr int WR = BM / 2;                 // rows per wave
  constexpr int MR = WR / 16;                // 4 or 2
  constexpr int ACH_PW = (BM / 8) / 8;       // A 1KB chunks per wave
  constexpr int BCH_PW = 4;                  // B 1KB chunks per wave
  __shared__ __align__(16) u16 As[BM * 64];
  __shared__ __align__(16) u16 Bs[BN * 64];

  const int tid = threadIdx.x, lane = tid & 63, wid = tid >> 6;
  const int wm = wid >> 2, wn = wid & 3;

  // XCD-chunked swizzle (grids always %8==0), row-major (mb,nb)
  const int ncol = N / BN;
  const int nwg = gridDim.x;
  const int bid = blockIdx.x;
  const int swz = (bid & 7) * (nwg >> 3) + (bid >> 3);
  const int mb = swz / ncol, nb = swz - mb * ncol;
  const int m0 = mb * BM, n0 = nb * BN;

  const int lrow8 = lane >> 3;               // row within 8-row chunk
  const int cg = (lane & 7) ^ lrow8;         // pre-swizzled global 16B-slot

  f32x4 acc[MR][4] = {};
  for (int kt = 0; kt < K; kt += 64) {
    #pragma unroll
    for (int it = 0; it < ACH_PW; it++) {
      int ca = wid * ACH_PW + it;
      int row = ca * 8 + lrow8;
      gload16(A + (size_t)(m0 + row) * K + kt + cg * 8, (u16*)As + ca * 512);
    }
    #pragma unroll
    for (int it = 0; it < BCH_PW; it++) {
      int cb = wid * BCH_PW + it;
      int row = cb * 8 + lrow8;
      gload16(Bt + (size_t)(n0 + row) * K + kt + cg * 8, (u16*)Bs + cb * 512);
    }
    __syncthreads();
    const int lr = lane & 15, hi = lane >> 4;
    #pragma unroll
    for (int kk = 0; kk < 2; kk++) {
      const int slot = (kk * 4 + hi) ^ (lr & 7);
      bf16x8 af[MR], bfr[4];
      #pragma unroll
      for (int m = 0; m < MR; m++)
        af[m] = *(const bf16x8*)&As[(wm * WR + m * 16 + lr) * 64 + slot * 8];
      #pragma unroll
      for (int n = 0; n < 4; n++)
        bfr[n] = *(const bf16x8*)&Bs[(wn * 64 + n * 16 + lr) * 64 + slot * 8];
      #pragma unroll
      for (int m = 0; m < MR; m++)
        #pragma unroll
        for (int n = 0; n < 4; n++)
          acc[m][n] = __builtin_amdgcn_mfma_f32_16x16x32_bf16(af[m], bfr[n], acc[m][n], 0, 0, 0);
    }
    __syncthreads();
  }

  const int lr = lane & 15, hi = lane >> 4;
  if constexpr (EPI == 0) {
    const int bsel = n0 >> 8;
    u16* C = (bsel == 0) ? C0 : ((bsel == 1) ? C1 : C2);
    #pragma unroll
    for (int m = 0; m < MR; m++)
      #pragma unroll
      for (int n = 0; n < 4; n++)
        #pragma unroll
        for (int r = 0; r < 4; r++) {
          int row = m0 + wm * WR + m * 16 + hi * 4 + r;
          int col = wn * 64 + n * 16 + lr;
          C[(size_t)row * 256 + col] = f2bf(acc[m][n][r]);
        }
  } else if constexpr (EPI == 1) {
    #pragma unroll
    for (int m = 0; m < MR; m++)
      #pragma unroll
      for (int n = 0; n < 4; n++)
        #pragma unroll
        for (int r = 0; r < 4; r++) {
          int row = m0 + wm * WR + m * 16 + hi * 4 + r;
          int col = n0 + wn * 64 + n * 16 + lr;
          float v = fmaxf(acc[m][n][r] + bias[col], 0.f);
          C0[(size_t)row * N + col] = f2bf(v);
        }
  } else {  // EPI 2 / 4: full-row (BN=256) LN epilogues
    __shared__ float rsum[BM], rsq[BM];
    if (tid < BM) { rsum[tid] = 0.f; rsq[tid] = 0.f; }
    __syncthreads();
    #pragma unroll
    for (int m = 0; m < MR; m++)
      #pragma unroll
      for (int n = 0; n < 4; n++)
        #pragma unroll
        for (int r = 0; r < 4; r++) {
          int rl = wm * WR + m * 16 + hi * 4 + r;
          int col = wn * 64 + n * 16 + lr;
          size_t gi = (size_t)(m0 + rl) * 256 + col;
          float v = acc[m][n][r] + bias[col];
          float x;
          if constexpr (EPI == 2) {
            v = fmaxf(v, 0.f);
            C0[gi] = f2bf(v);            // h2
            x = b2f(resbf[gi]) + v;      // e + h
          } else {
            x = b2f(resbf[gi]) + v;      // out1 + ffn
          }
          acc[m][n][r] = x;
        }
    #pragma unroll
    for (int m = 0; m < MR; m++)
      #pragma unroll
      for (int r = 0; r < 4; r++) {
        float s = 0.f, q = 0.f;
        #pragma unroll
        for (int n = 0; n < 4; n++) { float x = acc[m][n][r]; s += x; q += x * x; }
        #pragma unroll
        for (int off = 1; off < 16; off <<= 1) {
          s += __shfl_xor(s, off);
          q += __shfl_xor(q, off);
        }
        if (lr == 0) {
          int rl = wm * WR + m * 16 + hi * 4 + r;
          atomicAdd(&rsum[rl], s);
          atomicAdd(&rsq[rl], q);
        }
      }
    __syncthreads();
    #pragma unroll
    for (int m = 0; m < MR; m++)
      #pragma unroll
      for (int n = 0; n < 4; n++)
        #pragma unroll
        for (int r = 0; r < 4; r++) {
          int rl = wm * WR + m * 16 + hi * 4 + r;
          int col = wn * 64 + n * 16 + lr;
          size_t gi = (size_t)(m0 + rl) * 256 + col;
          float mu = rsum[rl] * (1.f / 256.f);
          float var = rsq[rl] * (1.f / 256.f) - mu * mu;
          float rstd = rsqrtf(fmaxf(var, 0.f) + 1e-6f);
          float o = g[col] * (acc[m][n][r] - mu) * rstd + be[col];
          if constexpr (EPI == 2) C1[gi] = f2bf(o);   // out1 bf16
          else                    Fout[gi] = o;       // out2 f32
        }
  }
}

// ---------------- small f32 GEMMs for s-vectors (opt. fused mean) ----------
__global__ LCONST void sgemm3_kernel(const float* __restrict__ X, const float* __restrict__ part,
                                     const float* __restrict__ Wq, const float* __restrict__ Wk,
                                     const float* __restrict__ Wv, float* __restrict__ Yq,
                                     float* __restrict__ Yk, float* __restrict__ Yv) {
  __shared__ float xs[256];
  int b = blockIdx.x, sel = blockIdx.y, tid = threadIdx.x;
  if (part) {
    float s = 0.f;
    #pragma unroll
    for (int c = 0; c < 32; c++) s += part[((size_t)b * 32 + c) * 256 + tid];
    xs[tid] = s * (1.f / 2048.f);
  } else {
    xs[tid] = X[b * 256 + tid];
  }
  __syncthreads();
  const float* W = (sel == 0) ? Wq : ((sel == 1) ? Wk : Wv);
  float* Y = (sel == 0) ? Yq : ((sel == 1) ? Yk : Yv);
  float acc = 0.f;
  #pragma unroll 4
  for (int d = 0; d < 256; d++) acc = fmaf(xs[d], W[(size_t)d * 256 + tid], acc);
  Y[b * 256 + tid] = acc;
}

// ---------------- fused 5-key per-token attention (MHA1 core) --------------
__global__ LCONST void attn1_kernel(const u16* __restrict__ hq, const u16* __restrict__ pk,
                                    const u16* __restrict__ pv, const u16* __restrict__ ek,
                                    const u16* __restrict__ ev, const float* __restrict__ skp,
                                    const float* __restrict__ svp, u16* __restrict__ outp) {
  int t = blockIdx.x * 256 + threadIdx.x;     // B*L*H threads
  int h = t & 7;
  size_t token = (size_t)(t >> 3);
  int b = (int)(token >> 11);
  int i = (int)(token & 2047);
  size_t tb = (size_t)b << 11;
  size_t ip = tb + ((i + 1) & 2047);
  size_t im = tb + ((i + 2047) & 2047);
  const int off = h * 32;

  float qf[32];
  {
    const u16* q = hq + token * 256 + off;
    #pragma unroll
    for (int c = 0; c < 4; c++) {
      uint4 u = *(const uint4*)(q + c * 8);
      qf[c*8+0] = bflo(u.x); qf[c*8+1] = bfhi(u.x);
      qf[c*8+2] = bflo(u.y); qf[c*8+3] = bfhi(u.y);
      qf[c*8+4] = bflo(u.z); qf[c*8+5] = bfhi(u.z);
      qf[c*8+6] = bflo(u.w); qf[c*8+7] = bfhi(u.w);
    }
  }
  const u16* kr0 = pk + ip * 256 + off;
  const u16* kr1 = pk + token * 256 + off;
  const u16* kr2 = pk + im * 256 + off;
  const u16* kr3 = ek + token * 256 + off;
  float lg[5];
  {
    float d0 = 0, d1 = 0, d2 = 0, d3 = 0;
    #pragma unroll
    for (int cc = 0; cc < 4; cc++) {
      d0 += dot8(*(const uint4*)(kr0 + cc * 8), qf + cc * 8);
      d1 += dot8(*(const uint4*)(kr1 + cc * 8), qf + cc * 8);
      d2 += dot8(*(const uint4*)(kr2 + cc * 8), qf + cc * 8);
      d3 += dot8(*(const uint4*)(kr3 + cc * 8), qf + cc * 8);
    }
    lg[0] = d0; lg[1] = d1; lg[2] = d2; lg[3] = d3;
    float d4 = 0;
    const float* s = skp + b * 256 + off;
    #pragma unroll
    for (int j = 0; j < 32; j++) d4 = fmaf(qf[j], s[j], d4);
    lg[4] = d4;
  }
  const float sc = 0.17677669529663687f;      // 1/sqrt(32)
  float m = lg[0];
  #pragma unroll
  for (int c = 1; c < 5; c++) m = fmaxf(m, lg[c]);
  float w[5], den = 0.f;
  #pragma unroll
  for (int c = 0; c < 5; c++) { w[c] = __expf((lg[c] - m) * sc); den += w[c]; }

  float a[32];
  #pragma unroll
  for (int j = 0; j < 32; j++) a[j] = 0.f;
  const u16* vr0 = pv + ip * 256 + off;
  const u16* vr1 = pv + token * 256 + off;
  const u16* vr2 = pv + im * 256 + off;
  const u16* vr3 = ev + token * 256 + off;
  #pragma unroll
  for (int cc = 0; cc < 4; cc++) {
    fma8(*(const uint4*)(vr0 + cc * 8), w[0], a + cc * 8);
    fma8(*(const uint4*)(vr1 + cc * 8), w[1], a + cc * 8);
    fma8(*(const uint4*)(vr2 + cc * 8), w[2], a + cc * 8);
    fma8(*(const uint4*)(vr3 + cc * 8), w[3], a + cc * 8);
  }
  {
    const float* s = svp + b * 256 + off;
    #pragma unroll
    for (int j = 0; j < 32; j++) a[j] = fmaf(w[4], s[j], a[j]);
  }
  float inv = 1.f / den;
  u16* o = outp + token * 256 + off;
  #pragma unroll
  for (int c = 0; c < 4; c++) {
    uint4 u;
    u.x = (u32)f2bf(a[c*8+0] * inv) | ((u32)f2bf(a[c*8+1] * inv) << 16);
    u.y = (u32)f2bf(a[c*8+2] * inv) | ((u32)f2bf(a[c*8+3] * inv) << 16);
    u.z = (u32)f2bf(a[c*8+4] * inv) | ((u32)f2bf(a[c*8+5] * inv) << 16);
    u.w = (u32)f2bf(a[c*8+6] * inv) | ((u32)f2bf(a[c*8+7] * inv) << 16);
    *(uint4*)(o + c * 8) = u;
  }
}

// ---------------- MHA2 split: 4 key-chunks per (b,h) -----------------------
// partial[blk*36]: [0]=m, [1]=l, [2..33]=acc
__global__ LCONST void mha2a_kernel(const float* __restrict__ sqp, const float* __restrict__ skp,
                                    const float* __restrict__ svp, const u16* __restrict__ pk,
                                    const u16* __restrict__ pv, float* __restrict__ partial) {
  __shared__ float rmax[4], rsum[4], racc[4][32];
  const int blk = blockIdx.x;                 // bh*4 + c
  const int bh = blk >> 2, c = blk & 3;
  const int b = bh >> 3, h = bh & 7;
  const int tid = threadIdx.x;
  const int lane = tid & 63, wid = tid >> 6;
  const int off = h * 32;
  const float sc = 0.17677669529663687f;

  float qf[32];
  {
    const float* q = sqp + b * 256 + off;
    #pragma unroll
    for (int j = 0; j < 32; j++) qf[j] = q[j];
  }
  const int k0 = c * 512 + tid;               // two h-keys per thread
  const int k1 = k0 + 256;
  const u16* kp0 = pk + ((size_t)b * 2048 + k0) * 256 + off;
  const u16* kp1 = pk + ((size_t)b * 2048 + k1) * 256 + off;
  float d0 = 0.f, d1 = 0.f;
  #pragma unroll
  for (int cc = 0; cc < 4; cc++) {
    d0 += dot8(*(const uint4*)(kp0 + cc * 8), qf + cc * 8);
    d1 += dot8(*(const uint4*)(kp1 + cc * 8), qf + cc * 8);
  }
  d0 *= sc; d1 *= sc;
  float ds = -1e30f;
  if (c == 0 && tid == 0) {                   // the s-key
    float d = 0.f;
    const float* k = skp + b * 256 + off;
    #pragma unroll
    for (int j = 0; j < 32; j++) d = fmaf(qf[j], k[j], d);
    ds = d * sc;
  }
  float lmax = fmaxf(fmaxf(d0, d1), ds);
  #pragma unroll
  for (int o = 32; o; o >>= 1) lmax = fmaxf(lmax, __shfl_down(lmax, o));
  if (lane == 0) rmax[wid] = lmax;
  __syncthreads();
  const float M = fmaxf(fmaxf(rmax[0], rmax[1]), fmaxf(rmax[2], rmax[3]));

  float w0 = __expf(d0 - M), w1 = __expf(d1 - M);
  float lsum = w0 + w1;
  float a[32];
  #pragma unroll
  for (int j = 0; j < 32; j++) a[j] = 0.f;
  const u16* vp0 = pv + ((size_t)b * 2048 + k0) * 256 + off;
  const u16* vp1 = pv + ((size_t)b * 2048 + k1) * 256 + off;
  #pragma unroll
  for (int cc = 0; cc < 4; cc++) {
    fma8(*(const uint4*)(vp0 + cc * 8), w0, a + cc * 8);
    fma8(*(const uint4*)(vp1 + cc * 8), w1, a + cc * 8);
  }
  if (c == 0 && tid == 0) {
    float ws = __expf(ds - M);
    lsum += ws;
    const float* v = svp + b * 256 + off;
    #pragma unroll
    for (int j = 0; j < 32; j++) a[j] = fmaf(ws, v[j], a[j]);
  }
  #pragma unroll
  for (int o = 32; o; o >>= 1) lsum += __shfl_down(lsum, o);
  if (lane == 0) rsum[wid] = lsum;
  #pragma unroll
  for (int j = 0; j < 32; j++) {
    float v = a[j];
    #pragma unroll
    for (int o = 32; o; o >>= 1) v += __shfl_down(v, o);
    if (lane == 0) racc[wid][j] = v;
  }
  __syncthreads();
  float* P = partial + (size_t)blk * 36;
  if (tid < 32) {
    P[2 + tid] = racc[0][tid] + racc[1][tid] + racc[2][tid] + racc[3][tid];
    if (tid == 0) {
      P[0] = M;
      P[1] = rsum[0] + rsum[1] + rsum[2] + rsum[3];
    }
  }
}

// ---------------- MHA2 combine + s = relu(attn2@Wo+bo) [+ q/k/v proj] ------
template <bool PROJ>
__global__ LCONST void mha2c_kernel(const float* __restrict__ partial,
                                    const float* __restrict__ Wo, const float* __restrict__ bo,
                                    const float* __restrict__ Wq, const float* __restrict__ Wk,
                                    const float* __restrict__ Wv,
                                    float* __restrict__ Y, float* __restrict__ Yq,
                                    float* __restrict__ Yk, float* __restrict__ Yv) {
  __shared__ float xs[256];
  __shared__ float ss[256];
  const int b = blockIdx.x, tid = threadIdx.x;
  {
    int hh = tid >> 5, d = tid & 31;
    const float* P = partial + (size_t)(b * 8 + hh) * 4 * 36;
    float M = fmaxf(fmaxf(P[0], P[36]), fmaxf(P[72], P[108]));
    float l = 0.f, o = 0.f;
    #pragma unroll
    for (int c = 0; c < 4; c++) {
      float f = __expf(P[c * 36] - M);
      l += f * P[c * 36 + 1];
      o += f * P[c * 36 + 2 + d];
    }
    xs[tid] = o / l;
  }
  __syncthreads();
  float acc = 0.f;
  #pragma unroll 4
  for (int d = 0; d < 256; d++) acc = fmaf(xs[d], Wo[(size_t)d * 256 + tid], acc);
  acc = fmaxf(acc + bo[tid], 0.f);
  Y[b * 256 + tid] = acc;
  if constexpr (PROJ) {
    ss[tid] = acc;
    __syncthreads();
    float aq = 0.f, ak = 0.f, av = 0.f;
    #pragma unroll 4
    for (int d = 0; d < 256; d++) {
      float x = ss[d];
      aq = fmaf(x, Wq[(size_t)d * 256 + tid], aq);
      ak = fmaf(x, Wk[(size_t)d * 256 + tid], ak);
      av = fmaf(x, Wv[(size_t)d * 256 + tid], av);
    }
    Yq[b * 256 + tid] = aq;
    Yk[b * 256 + tid] = ak;
    Yv[b * 256 + tid] = av;
  }
}

// ===========================================================================
extern "C" void kernel_launch(void* const* d_in, const int* in_sizes, int n_in,
                              void* d_out, int out_size, void* d_ws, size_t ws_size,
                              hipStream_t stream) {
  const float* e   = (const float*)d_in[0];
  const float* Wq  = (const float*)d_in[1];
  const float* Wk  = (const float*)d_in[2];
  const float* Wv  = (const float*)d_in[3];
  const float* Wo  = (const float*)d_in[4];
  const float* bo  = (const float*)d_in[5];
  const float* W1  = (const float*)d_in[6];
  const float* b1  = (const float*)d_in[7];
  const float* W2  = (const float*)d_in[8];
  const float* b2  = (const float*)d_in[9];
  const float* g1  = (const float*)d_in[10];
  const float* be1 = (const float*)d_in[11];
  const float* g2  = (const float*)d_in[12];
  const float* be2 = (const float*)d_in[13];

  char* wsb = (char*)d_ws;
  size_t off = 0;
  auto alc = [&](size_t n) { void* p = wsb + off; off += (n + 255) & ~(size_t)255; return p; };
  u16* Wqkv_t = (u16*)alc(768 * 256 * 2);     // rows 0-255 Wq, 256-511 Wk, 512-767 Wv
  u16* Wo_t   = (u16*)alc(65536 * 2);
  u16* W1_t   = (u16*)alc(262144 * 2);
  u16* W2_t   = (u16*)alc(262144 * 2);
  float* sB    = (float*)alc(4096 * 4);
  float* sqp   = (float*)alc(4096 * 4);
  float* skp   = (float*)alc(4096 * 4);
  float* svp   = (float*)alc(4096 * 4);
  float* partM = (float*)alc(512 * 36 * 4);
  float* part  = (float*)alc(524288);
  const size_t SZ = 16777216;                 // 32768*256*2 bytes
  u16* hq   = (u16*)alc(SZ);                  // ffn1 aliases hq..pk (64 MB)
  u16* ek   = (u16*)alc(SZ);
  u16* ev   = (u16*)alc(SZ);
  u16* pk   = (u16*)alc(SZ);
  u16* pv   = (u16*)alc(SZ);
  u16* ao   = (u16*)alc(SZ);
  u16* hbuf = (u16*)alc(SZ);
  u16* ebf  = (u16*)alc(SZ);
  u16* out1 = (u16*)alc(SZ);
  u16* ffn1 = hq;

  const int M = 32768;
  float* outp  = (float*)d_out;
  float* s_out = outp + 8388608;

  // ---- prep: weights -> bf16 transposed + partial mean + e->bf16 ----
  prep_kernel<<<3584, 256, 0, stream>>>(e, Wq, Wk, Wv, Wo, W1, W2,
      Wqkv_t, Wo_t, W1_t, W2_t, part, ebf);

  // ---------------- cycle 1 (h = e, s = s0) ----------------
  sgemm3_kernel<<<dim3(16, 3), 256, 0, stream>>>(nullptr, part, Wq, Wk, Wv, sqp, skp, svp);
  gemm3_kernel<128, 256, 0><<<768, 512, 0, stream>>>(ebf, Wqkv_t, nullptr, hq, ek, ev,
      nullptr, nullptr, nullptr, nullptr, M, 768, 256);
  attn1_kernel<<<1024, 256, 0, stream>>>(hq, ek, ev, ek, ev, skp, svp, ao);
  gemm3_kernel<64, 256, 1><<<512, 512, 0, stream>>>(ao, Wo_t, bo, hbuf, nullptr, nullptr,
      nullptr, nullptr, nullptr, nullptr, M, 256, 256);
  gemm3_kernel<128, 256, 0><<<768, 512, 0, stream>>>(hbuf, Wqkv_t, nullptr, hq, pk, pv,
      nullptr, nullptr, nullptr, nullptr, M, 768, 256);   // hq2, pk, pv
  mha2a_kernel<<<512, 256, 0, stream>>>(sqp, skp, svp, pk, pv, partM);
  mha2c_kernel<true><<<16, 256, 0, stream>>>(partM, Wo, bo, Wq, Wk, Wv,
      sB, sqp, skp, svp);                                 // s1 + its q/k/v projections

  // ---------------- cycle 2 (h = h1, s = s1) ----------------
  attn1_kernel<<<1024, 256, 0, stream>>>(hq, pk, pv, ek, ev, skp, svp, ao);
  gemm3_kernel<64, 256, 2><<<512, 512, 0, stream>>>(ao, Wo_t, bo, hbuf, out1, nullptr,
      ebf, g1, be1, nullptr, M, 256, 256);                // h2 + fused LN1
  gemm3_kernel<128, 256, 0><<<512, 512, 0, stream>>>(hbuf, Wqkv_t + 65536, nullptr, pk, pv, nullptr,
      nullptr, nullptr, nullptr, nullptr, M, 512, 256);   // pk2, pv2
  mha2a_kernel<<<512, 256, 0, stream>>>(sqp, skp, svp, pk, pv, partM);
  mha2c_kernel<false><<<16, 256, 0, stream>>>(partM, Wo, bo, nullptr, nullptr, nullptr,
      s_out, nullptr, nullptr, nullptr);                  // s output

  // ---------------- epilogue: FFN (LN1/LN2 fused into GEMMs) ----------------
  gemm3_kernel<128, 256, 1><<<1024, 512, 0, stream>>>(out1, W1_t, b1, ffn1, nullptr, nullptr,
      nullptr, nullptr, nullptr, nullptr, M, 1024, 256);
  gemm3_kernel<64, 256, 4><<<512, 512, 0, stream>>>(ffn1, W2_t, b2, nullptr, nullptr, nullptr,
      out1, g2, be2, outp, M, 256, 1024);
  (void)in_sizes; (void)n_in; (void)out_size; (void)ws_size;
}

// Round 5
// 278.292 us; speedup vs baseline: 1.8133x; 1.1962x over previous
//
#include <hip/hip_runtime.h>

typedef unsigned short u16;
typedef unsigned int u32;
typedef __attribute__((ext_vector_type(8))) short bf16x8;
typedef __attribute__((ext_vector_type(4))) float f32x4;

#define LCONST __launch_bounds__(256)

__device__ __forceinline__ u16 f2bf(float f) {
  u32 u = __float_as_uint(f);
  u32 r = (u + 0x7FFFu + ((u >> 16) & 1u)) >> 16;
  return (u16)r;
}
__device__ __forceinline__ float bflo(u32 w) { return __uint_as_float(w << 16); }
__device__ __forceinline__ float bfhi(u32 w) { return __uint_as_float(w & 0xFFFF0000u); }
__device__ __forceinline__ float b2f(u16 v) { return __uint_as_float(((u32)v) << 16); }

__device__ __forceinline__ float dot8(uint4 u, const float* q) {
  return q[0]*bflo(u.x) + q[1]*bfhi(u.x) + q[2]*bflo(u.y) + q[3]*bfhi(u.y)
       + q[4]*bflo(u.z) + q[5]*bfhi(u.z) + q[6]*bflo(u.w) + q[7]*bfhi(u.w);
}
__device__ __forceinline__ void fma8(uint4 u, float wt, float* a) {
  a[0] = fmaf(wt, bflo(u.x), a[0]); a[1] = fmaf(wt, bfhi(u.x), a[1]);
  a[2] = fmaf(wt, bflo(u.y), a[2]); a[3] = fmaf(wt, bfhi(u.y), a[3]);
  a[4] = fmaf(wt, bflo(u.z), a[4]); a[5] = fmaf(wt, bfhi(u.z), a[5]);
  a[6] = fmaf(wt, bflo(u.w), a[6]); a[7] = fmaf(wt, bfhi(u.w), a[7]);
}

// async global -> LDS, 16 bytes per lane. LDS dest = wave-uniform base + lane*16.
__device__ __forceinline__ void gload16(const u16* g, u16* l) {
  __builtin_amdgcn_global_load_lds(
      (const __attribute__((address_space(1))) unsigned int*)g,
      (__attribute__((address_space(3))) unsigned int*)l, 16, 0, 0);
}

// ---------------- prep: all weight transpose-casts + e-mean (one launch) ---
__global__ LCONST void prep_kernel(const float* __restrict__ e,
                                   const float* __restrict__ Wq, const float* __restrict__ Wk,
                                   const float* __restrict__ Wv, const float* __restrict__ Wo,
                                   const float* __restrict__ W1, const float* __restrict__ W2,
                                   u16* __restrict__ Wqkv_t, u16* __restrict__ Wo_t,
                                   u16* __restrict__ W1_t, u16* __restrict__ W2_t,
                                   float* __restrict__ part, u16* __restrict__ ebf) {
  int blk = blockIdx.x;
  int tid = threadIdx.x;
  if (blk < 3072) {                               // weight transpose-casts
    int idx = blk * 256 + tid;                    // 786432 total
    if (idx < 196608) {                           // Wq|Wk|Wv (256x256 each)
      int sub = idx >> 16, r = idx & 65535;
      int n = r >> 8, k = r & 255;
      const float* src = (sub == 0) ? Wq : ((sub == 1) ? Wk : Wv);
      Wqkv_t[idx] = f2bf(src[(size_t)k * 256 + n]);
    } else if (idx < 262144) {                    // Wo (256x256)
      int r = idx - 196608;
      int n = r >> 8, k = r & 255;
      Wo_t[r] = f2bf(Wo[(size_t)k * 256 + n]);
    } else if (idx < 524288) {                    // W1 (256x1024) -> [1024][256]
      int r = idx - 262144;
      int n = r >> 8, k = r & 255;
      W1_t[r] = f2bf(W1[(size_t)k * 1024 + n]);
    } else {                                      // W2 (1024x256) -> [256][1024]
      int r = idx - 524288;
      int n = r >> 10, k = r & 1023;
      W2_t[r] = f2bf(W2[(size_t)k * 256 + n]);
    }
  } else {                                        // partial mean + e->bf16
    int mb = blk - 3072;                          // 512 blocks
    int b = mb >> 5, c = mb & 31;
    size_t base = ((size_t)b * 2048 + (size_t)c * 64) * 256 + tid;
    float s = 0.f;
    #pragma unroll 8
    for (int i = 0; i < 64; i++) {
      float v = e[base + (size_t)i * 256];
      s += v;
      ebf[base + (size_t)i * 256] = f2bf(v);
    }
    part[(size_t)mb * 256 + tid] = s;
  }
}

// ---------------- MFMA GEMM: C = A(MxK,bf16) * Bt(NxK,bf16)^T --------------
// 512 threads, 2x4 waves. (BM,BN)=(128,256): wave 64x64, MR=4.
//                          (BM,BN)=(64,256):  wave 32x64, MR=2.
// EPI: 0 = plain bf16 store routed into 256-wide buffers C0/C1/C2 by col>>8
//      1 = relu(acc+bias) -> bf16 C0 (stride N)
//      2 = Wo+LN1: h=relu(acc+bias)->C0; out1=LN(resbf+h)->C1 (bf16)
//      4 = FFN2+LN2: x=acc+bias+resbf; LN(x) -> Fout (f32)
template <int BM, int BN, int EPI>
__global__ __launch_bounds__(512, (BM == 128) ? 4 : 6)
void gemm3_kernel(const u16* __restrict__ A, const u16* __restrict__ Bt,
                  const float* __restrict__ bias,
                  u16* __restrict__ C0, u16* __restrict__ C1, u16* __restrict__ C2,
                  const u16* __restrict__ resbf,
                  const float* __restrict__ g, const float* __restrict__ be,
                  float* __restrict__ Fout,
                  int M, int N, int K) {
  constexpr int WR = BM / 2;                 // rows per wave
  constexpr int MR = WR / 16;                // 4 or 2
  constexpr int ACH_PW = (BM / 8) / 8;       // A 1KB chunks per wave
  constexpr int BCH_PW = 4;                  // B 1KB chunks per wave
  __shared__ __align__(16) u16 As[BM * 64];
  __shared__ __align__(16) u16 Bs[BN * 64];

  const int tid = threadIdx.x, lane = tid & 63, wid = tid >> 6;
  const int wm = wid >> 2, wn = wid & 3;

  // XCD-chunked swizzle (grids always %8==0), row-major (mb,nb)
  const int ncol = N / BN;
  const int nwg = gridDim.x;
  const int bid = blockIdx.x;
  const int swz = (bid & 7) * (nwg >> 3) + (bid >> 3);
  const int mb = swz / ncol, nb = swz - mb * ncol;
  const int m0 = mb * BM, n0 = nb * BN;

  const int lrow8 = lane >> 3;               // row within 8-row chunk
  const int cg = (lane & 7) ^ lrow8;         // pre-swizzled global 16B-slot

  f32x4 acc[MR][4] = {};
  for (int kt = 0; kt < K; kt += 64) {
    #pragma unroll
    for (int it = 0; it < ACH_PW; it++) {
      int ca = wid * ACH_PW + it;
      int row = ca * 8 + lrow8;
      gload16(A + (size_t)(m0 + row) * K + kt + cg * 8, (u16*)As + ca * 512);
    }
    #pragma unroll
    for (int it = 0; it < BCH_PW; it++) {
      int cb = wid * BCH_PW + it;
      int row = cb * 8 + lrow8;
      gload16(Bt + (size_t)(n0 + row) * K + kt + cg * 8, (u16*)Bs + cb * 512);
    }
    __syncthreads();
    const int lr = lane & 15, hi = lane >> 4;
    #pragma unroll
    for (int kk = 0; kk < 2; kk++) {
      const int slot = (kk * 4 + hi) ^ (lr & 7);
      bf16x8 af[MR], bfr[4];
      #pragma unroll
      for (int m = 0; m < MR; m++)
        af[m] = *(const bf16x8*)&As[(wm * WR + m * 16 + lr) * 64 + slot * 8];
      #pragma unroll
      for (int n = 0; n < 4; n++)
        bfr[n] = *(const bf16x8*)&Bs[(wn * 64 + n * 16 + lr) * 64 + slot * 8];
      #pragma unroll
      for (int m = 0; m < MR; m++)
        #pragma unroll
        for (int n = 0; n < 4; n++)
          acc[m][n] = __builtin_amdgcn_mfma_f32_16x16x32_bf16(af[m], bfr[n], acc[m][n], 0, 0, 0);
    }
    __syncthreads();
  }

  const int lr = lane & 15, hi = lane >> 4;
  if constexpr (EPI == 0) {
    const int bsel = n0 >> 8;
    u16* C = (bsel == 0) ? C0 : ((bsel == 1) ? C1 : C2);
    #pragma unroll
    for (int m = 0; m < MR; m++)
      #pragma unroll
      for (int n = 0; n < 4; n++)
        #pragma unroll
        for (int r = 0; r < 4; r++) {
          int row = m0 + wm * WR + m * 16 + hi * 4 + r;
          int col = wn * 64 + n * 16 + lr;
          C[(size_t)row * 256 + col] = f2bf(acc[m][n][r]);
        }
  } else if constexpr (EPI == 1) {
    #pragma unroll
    for (int m = 0; m < MR; m++)
      #pragma unroll
      for (int n = 0; n < 4; n++)
        #pragma unroll
        for (int r = 0; r < 4; r++) {
          int row = m0 + wm * WR + m * 16 + hi * 4 + r;
          int col = n0 + wn * 64 + n * 16 + lr;
          float v = fmaxf(acc[m][n][r] + bias[col], 0.f);
          C0[(size_t)row * N + col] = f2bf(v);
        }
  } else {  // EPI 2 / 4: full-row (BN=256) LN epilogues
    __shared__ float rsum[BM], rsq[BM];
    if (tid < BM) { rsum[tid] = 0.f; rsq[tid] = 0.f; }
    __syncthreads();
    #pragma unroll
    for (int m = 0; m < MR; m++)
      #pragma unroll
      for (int n = 0; n < 4; n++)
        #pragma unroll
        for (int r = 0; r < 4; r++) {
          int rl = wm * WR + m * 16 + hi * 4 + r;
          int col = wn * 64 + n * 16 + lr;
          size_t gi = (size_t)(m0 + rl) * 256 + col;
          float v = acc[m][n][r] + bias[col];
          float x;
          if constexpr (EPI == 2) {
            v = fmaxf(v, 0.f);
            C0[gi] = f2bf(v);            // h2
            x = b2f(resbf[gi]) + v;      // e + h
          } else {
            x = b2f(resbf[gi]) + v;      // out1 + ffn
          }
          acc[m][n][r] = x;
        }
    #pragma unroll
    for (int m = 0; m < MR; m++)
      #pragma unroll
      for (int r = 0; r < 4; r++) {
        float s = 0.f, q = 0.f;
        #pragma unroll
        for (int n = 0; n < 4; n++) { float x = acc[m][n][r]; s += x; q += x * x; }
        #pragma unroll
        for (int off = 1; off < 16; off <<= 1) {
          s += __shfl_xor(s, off);
          q += __shfl_xor(q, off);
        }
        if (lr == 0) {
          int rl = wm * WR + m * 16 + hi * 4 + r;
          atomicAdd(&rsum[rl], s);
          atomicAdd(&rsq[rl], q);
        }
      }
    __syncthreads();
    #pragma unroll
    for (int m = 0; m < MR; m++)
      #pragma unroll
      for (int n = 0; n < 4; n++)
        #pragma unroll
        for (int r = 0; r < 4; r++) {
          int rl = wm * WR + m * 16 + hi * 4 + r;
          int col = wn * 64 + n * 16 + lr;
          size_t gi = (size_t)(m0 + rl) * 256 + col;
          float mu = rsum[rl] * (1.f / 256.f);
          float var = rsq[rl] * (1.f / 256.f) - mu * mu;
          float rstd = rsqrtf(fmaxf(var, 0.f) + 1e-6f);
          float o = g[col] * (acc[m][n][r] - mu) * rstd + be[col];
          if constexpr (EPI == 2) C1[gi] = f2bf(o);   // out1 bf16
          else                    Fout[gi] = o;       // out2 f32
        }
  }
}

// ---------------- wide s-vector projections: Yq/Yk/Yv = X @ W --------------
// grid (16, 12): wsel = y>>2, 64-col chunk = y&3. 256 thr = 64 cols x 4 d-grps.
// MEAN: X comes from mean partials (part), else from X vector.
template <bool MEAN>
__global__ LCONST void proj_kernel(const float* __restrict__ X, const float* __restrict__ part,
                                   const float* __restrict__ Wq, const float* __restrict__ Wk,
                                   const float* __restrict__ Wv, float* __restrict__ Yq,
                                   float* __restrict__ Yk, float* __restrict__ Yv) {
  __shared__ float xs[256];
  __shared__ float red[256];
  const int b = blockIdx.x;
  const int wsel = blockIdx.y >> 2, n0 = (blockIdx.y & 3) * 64;
  const int tid = threadIdx.x;
  if constexpr (MEAN) {
    float s = 0.f;
    #pragma unroll
    for (int c = 0; c < 32; c++) s += part[((size_t)b * 32 + c) * 256 + tid];
    xs[tid] = s * (1.f / 2048.f);
  } else {
    xs[tid] = X[b * 256 + tid];
  }
  __syncthreads();
  const float* W = (wsel == 0) ? Wq : ((wsel == 1) ? Wk : Wv);
  float* Y = (wsel == 0) ? Yq : ((wsel == 1) ? Yk : Yv);
  const int c = tid & 63, g = tid >> 6;
  float p = 0.f;
  #pragma unroll 8
  for (int j = g * 64; j < g * 64 + 64; j++)
    p = fmaf(xs[j], W[(size_t)j * 256 + n0 + c], p);
  red[tid] = p;
  __syncthreads();
  if (g == 0)
    Y[b * 256 + n0 + c] = red[c] + red[64 + c] + red[128 + c] + red[192 + c];
}

// ---------------- fused 5-key per-token attention (MHA1 core) --------------
__global__ LCONST void attn1_kernel(const u16* __restrict__ hq, const u16* __restrict__ pk,
                                    const u16* __restrict__ pv, const u16* __restrict__ ek,
                                    const u16* __restrict__ ev, const float* __restrict__ skp,
                                    const float* __restrict__ svp, u16* __restrict__ outp) {
  int t = blockIdx.x * 256 + threadIdx.x;     // B*L*H threads
  int h = t & 7;
  size_t token = (size_t)(t >> 3);
  int b = (int)(token >> 11);
  int i = (int)(token & 2047);
  size_t tb = (size_t)b << 11;
  size_t ip = tb + ((i + 1) & 2047);
  size_t im = tb + ((i + 2047) & 2047);
  const int off = h * 32;

  float qf[32];
  {
    const u16* q = hq + token * 256 + off;
    #pragma unroll
    for (int c = 0; c < 4; c++) {
      uint4 u = *(const uint4*)(q + c * 8);
      qf[c*8+0] = bflo(u.x); qf[c*8+1] = bfhi(u.x);
      qf[c*8+2] = bflo(u.y); qf[c*8+3] = bfhi(u.y);
      qf[c*8+4] = bflo(u.z); qf[c*8+5] = bfhi(u.z);
      qf[c*8+6] = bflo(u.w); qf[c*8+7] = bfhi(u.w);
    }
  }
  const u16* kr0 = pk + ip * 256 + off;
  const u16* kr1 = pk + token * 256 + off;
  const u16* kr2 = pk + im * 256 + off;
  const u16* kr3 = ek + token * 256 + off;
  float lg[5];
  {
    float d0 = 0, d1 = 0, d2 = 0, d3 = 0;
    #pragma unroll
    for (int cc = 0; cc < 4; cc++) {
      d0 += dot8(*(const uint4*)(kr0 + cc * 8), qf + cc * 8);
      d1 += dot8(*(const uint4*)(kr1 + cc * 8), qf + cc * 8);
      d2 += dot8(*(const uint4*)(kr2 + cc * 8), qf + cc * 8);
      d3 += dot8(*(const uint4*)(kr3 + cc * 8), qf + cc * 8);
    }
    lg[0] = d0; lg[1] = d1; lg[2] = d2; lg[3] = d3;
    float d4 = 0;
    const float* s = skp + b * 256 + off;
    #pragma unroll
    for (int j = 0; j < 32; j++) d4 = fmaf(qf[j], s[j], d4);
    lg[4] = d4;
  }
  const float sc = 0.17677669529663687f;      // 1/sqrt(32)
  float m = lg[0];
  #pragma unroll
  for (int c = 1; c < 5; c++) m = fmaxf(m, lg[c]);
  float w[5], den = 0.f;
  #pragma unroll
  for (int c = 0; c < 5; c++) { w[c] = __expf((lg[c] - m) * sc); den += w[c]; }

  float a[32];
  #pragma unroll
  for (int j = 0; j < 32; j++) a[j] = 0.f;
  const u16* vr0 = pv + ip * 256 + off;
  const u16* vr1 = pv + token * 256 + off;
  const u16* vr2 = pv + im * 256 + off;
  const u16* vr3 = ev + token * 256 + off;
  #pragma unroll
  for (int cc = 0; cc < 4; cc++) {
    fma8(*(const uint4*)(vr0 + cc * 8), w[0], a + cc * 8);
    fma8(*(const uint4*)(vr1 + cc * 8), w[1], a + cc * 8);
    fma8(*(const uint4*)(vr2 + cc * 8), w[2], a + cc * 8);
    fma8(*(const uint4*)(vr3 + cc * 8), w[3], a + cc * 8);
  }
  {
    const float* s = svp + b * 256 + off;
    #pragma unroll
    for (int j = 0; j < 32; j++) a[j] = fmaf(w[4], s[j], a[j]);
  }
  float inv = 1.f / den;
  u16* o = outp + token * 256 + off;
  #pragma unroll
  for (int c = 0; c < 4; c++) {
    uint4 u;
    u.x = (u32)f2bf(a[c*8+0] * inv) | ((u32)f2bf(a[c*8+1] * inv) << 16);
    u.y = (u32)f2bf(a[c*8+2] * inv) | ((u32)f2bf(a[c*8+3] * inv) << 16);
    u.z = (u32)f2bf(a[c*8+4] * inv) | ((u32)f2bf(a[c*8+5] * inv) << 16);
    u.w = (u32)f2bf(a[c*8+6] * inv) | ((u32)f2bf(a[c*8+7] * inv) << 16);
    *(uint4*)(o + c * 8) = u;
  }
}

// ---------------- MHA2 split: 4 key-chunks per (b,h) -----------------------
// partial[blk*36]: [0]=m, [1]=l, [2..33]=acc
__global__ LCONST void mha2a_kernel(const float* __restrict__ sqp, const float* __restrict__ skp,
                                    const float* __restrict__ svp, const u16* __restrict__ pk,
                                    const u16* __restrict__ pv, float* __restrict__ partial) {
  __shared__ float rmax[4], rsum[4], racc[4][32];
  const int blk = blockIdx.x;                 // bh*4 + c
  const int bh = blk >> 2, c = blk & 3;
  const int b = bh >> 3, h = bh & 7;
  const int tid = threadIdx.x;
  const int lane = tid & 63, wid = tid >> 6;
  const int off = h * 32;
  const float sc = 0.17677669529663687f;

  float qf[32];
  {
    const float* q = sqp + b * 256 + off;
    #pragma unroll
    for (int j = 0; j < 32; j++) qf[j] = q[j];
  }
  const int k0 = c * 512 + tid;               // two h-keys per thread
  const int k1 = k0 + 256;
  const u16* kp0 = pk + ((size_t)b * 2048 + k0) * 256 + off;
  const u16* kp1 = pk + ((size_t)b * 2048 + k1) * 256 + off;
  float d0 = 0.f, d1 = 0.f;
  #pragma unroll
  for (int cc = 0; cc < 4; cc++) {
    d0 += dot8(*(const uint4*)(kp0 + cc * 8), qf + cc * 8);
    d1 += dot8(*(const uint4*)(kp1 + cc * 8), qf + cc * 8);
  }
  d0 *= sc; d1 *= sc;
  float ds = -1e30f;
  if (c == 0 && tid == 0) {                   // the s-key
    float d = 0.f;
    const float* k = skp + b * 256 + off;
    #pragma unroll
    for (int j = 0; j < 32; j++) d = fmaf(qf[j], k[j], d);
    ds = d * sc;
  }
  float lmax = fmaxf(fmaxf(d0, d1), ds);
  #pragma unroll
  for (int o = 32; o; o >>= 1) lmax = fmaxf(lmax, __shfl_down(lmax, o));
  if (lane == 0) rmax[wid] = lmax;
  __syncthreads();
  const float M = fmaxf(fmaxf(rmax[0], rmax[1]), fmaxf(rmax[2], rmax[3]));

  float w0 = __expf(d0 - M), w1 = __expf(d1 - M);
  float lsum = w0 + w1;
  float a[32];
  #pragma unroll
  for (int j = 0; j < 32; j++) a[j] = 0.f;
  const u16* vp0 = pv + ((size_t)b * 2048 + k0) * 256 + off;
  const u16* vp1 = pv + ((size_t)b * 2048 + k1) * 256 + off;
  #pragma unroll
  for (int cc = 0; cc < 4; cc++) {
    fma8(*(const uint4*)(vp0 + cc * 8), w0, a + cc * 8);
    fma8(*(const uint4*)(vp1 + cc * 8), w1, a + cc * 8);
  }
  if (c == 0 && tid == 0) {
    float ws = __expf(ds - M);
    lsum += ws;
    const float* v = svp + b * 256 + off;
    #pragma unroll
    for (int j = 0; j < 32; j++) a[j] = fmaf(ws, v[j], a[j]);
  }
  #pragma unroll
  for (int o = 32; o; o >>= 1) lsum += __shfl_down(lsum, o);
  if (lane == 0) rsum[wid] = lsum;
  #pragma unroll
  for (int j = 0; j < 32; j++) {
    float v = a[j];
    #pragma unroll
    for (int o = 32; o; o >>= 1) v += __shfl_down(v, o);
    if (lane == 0) racc[wid][j] = v;
  }
  __syncthreads();
  float* P = partial + (size_t)blk * 36;
  if (tid < 32) {
    P[2 + tid] = racc[0][tid] + racc[1][tid] + racc[2][tid] + racc[3][tid];
    if (tid == 0) {
      P[0] = M;
      P[1] = rsum[0] + rsum[1] + rsum[2] + rsum[3];
    }
  }
}

// ---------------- MHA2 combine + s = relu(attn2@Wo+bo), wide ---------------
// grid (16, 4): 64-col chunk per block. 256 thr = 64 cols x 4 d-groups.
__global__ LCONST void mha2c_kernel(const float* __restrict__ partial,
                                    const float* __restrict__ Wo, const float* __restrict__ bo,
                                    float* __restrict__ Y) {
  __shared__ float xs[256];
  __shared__ float red[256];
  const int b = blockIdx.x;
  const int n0 = blockIdx.y * 64;
  const int tid = threadIdx.x;
  {
    int hh = tid >> 5, d = tid & 31;
    const float* P = partial + (size_t)(b * 8 + hh) * 144;
    float M = fmaxf(fmaxf(P[0], P[36]), fmaxf(P[72], P[108]));
    float l = 0.f, o = 0.f;
    #pragma unroll
    for (int c = 0; c < 4; c++) {
      float f = __expf(P[c * 36] - M);
      l += f * P[c * 36 + 1];
      o += f * P[c * 36 + 2 + d];
    }
    xs[tid] = o / l;
  }
  __syncthreads();
  const int c = tid & 63, g = tid >> 6;
  float p = 0.f;
  #pragma unroll 8
  for (int j = g * 64; j < g * 64 + 64; j++)
    p = fmaf(xs[j], Wo[(size_t)j * 256 + n0 + c], p);
  red[tid] = p;
  __syncthreads();
  if (g == 0) {
    float v = red[c] + red[64 + c] + red[128 + c] + red[192 + c];
    Y[b * 256 + n0 + c] = fmaxf(v + bo[n0 + c], 0.f);
  }
}

// ===========================================================================
extern "C" void kernel_launch(void* const* d_in, const int* in_sizes, int n_in,
                              void* d_out, int out_size, void* d_ws, size_t ws_size,
                              hipStream_t stream) {
  const float* e   = (const float*)d_in[0];
  const float* Wq  = (const float*)d_in[1];
  const float* Wk  = (const float*)d_in[2];
  const float* Wv  = (const float*)d_in[3];
  const float* Wo  = (const float*)d_in[4];
  const float* bo  = (const float*)d_in[5];
  const float* W1  = (const float*)d_in[6];
  const float* b1  = (const float*)d_in[7];
  const float* W2  = (const float*)d_in[8];
  const float* b2  = (const float*)d_in[9];
  const float* g1  = (const float*)d_in[10];
  const float* be1 = (const float*)d_in[11];
  const float* g2  = (const float*)d_in[12];
  const float* be2 = (const float*)d_in[13];

  char* wsb = (char*)d_ws;
  size_t off = 0;
  auto alc = [&](size_t n) { void* p = wsb + off; off += (n + 255) & ~(size_t)255; return p; };
  u16* Wqkv_t = (u16*)alc(768 * 256 * 2);     // rows 0-255 Wq, 256-511 Wk, 512-767 Wv
  u16* Wo_t   = (u16*)alc(65536 * 2);
  u16* W1_t   = (u16*)alc(262144 * 2);
  u16* W2_t   = (u16*)alc(262144 * 2);
  float* sB    = (float*)alc(4096 * 4);
  float* sqp   = (float*)alc(4096 * 4);
  float* skp   = (float*)alc(4096 * 4);
  float* svp   = (float*)alc(4096 * 4);
  float* partM = (float*)alc(512 * 36 * 4);
  float* part  = (float*)alc(524288);
  const size_t SZ = 16777216;                 // 32768*256*2 bytes
  u16* hq   = (u16*)alc(SZ);                  // ffn1 aliases hq..pk (64 MB)
  u16* ek   = (u16*)alc(SZ);
  u16* ev   = (u16*)alc(SZ);
  u16* pk   = (u16*)alc(SZ);
  u16* pv   = (u16*)alc(SZ);
  u16* ao   = (u16*)alc(SZ);
  u16* hbuf = (u16*)alc(SZ);
  u16* ebf  = (u16*)alc(SZ);
  u16* out1 = (u16*)alc(SZ);
  u16* ffn1 = hq;

  const int M = 32768;
  float* outp  = (float*)d_out;
  float* s_out = outp + 8388608;

  // ---- prep: weights -> bf16 transposed + partial mean + e->bf16 ----
  prep_kernel<<<3584, 256, 0, stream>>>(e, Wq, Wk, Wv, Wo, W1, W2,
      Wqkv_t, Wo_t, W1_t, W2_t, part, ebf);

  // ---------------- cycle 1 (h = e, s = s0) ----------------
  proj_kernel<true><<<dim3(16, 12), 256, 0, stream>>>(nullptr, part, Wq, Wk, Wv, sqp, skp, svp);
  gemm3_kernel<128, 256, 0><<<768, 512, 0, stream>>>(ebf, Wqkv_t, nullptr, hq, ek, ev,
      nullptr, nullptr, nullptr, nullptr, M, 768, 256);
  attn1_kernel<<<1024, 256, 0, stream>>>(hq, ek, ev, ek, ev, skp, svp, ao);
  gemm3_kernel<64, 256, 1><<<512, 512, 0, stream>>>(ao, Wo_t, bo, hbuf, nullptr, nullptr,
      nullptr, nullptr, nullptr, nullptr, M, 256, 256);
  gemm3_kernel<128, 256, 0><<<768, 512, 0, stream>>>(hbuf, Wqkv_t, nullptr, hq, pk, pv,
      nullptr, nullptr, nullptr, nullptr, M, 768, 256);   // hq2, pk, pv
  mha2a_kernel<<<512, 256, 0, stream>>>(sqp, skp, svp, pk, pv, partM);
  mha2c_kernel<<<dim3(16, 4), 256, 0, stream>>>(partM, Wo, bo, sB);
  proj_kernel<false><<<dim3(16, 12), 256, 0, stream>>>(sB, nullptr, Wq, Wk, Wv, sqp, skp, svp);

  // ---------------- cycle 2 (h = h1, s = s1) ----------------
  attn1_kernel<<<1024, 256, 0, stream>>>(hq, pk, pv, ek, ev, skp, svp, ao);
  gemm3_kernel<64, 256, 2><<<512, 512, 0, stream>>>(ao, Wo_t, bo, hbuf, out1, nullptr,
      ebf, g1, be1, nullptr, M, 256, 256);                // h2 + fused LN1
  gemm3_kernel<128, 256, 0><<<512, 512, 0, stream>>>(hbuf, Wqkv_t + 65536, nullptr, pk, pv, nullptr,
      nullptr, nullptr, nullptr, nullptr, M, 512, 256);   // pk2, pv2
  mha2a_kernel<<<512, 256, 0, stream>>>(sqp, skp, svp, pk, pv, partM);
  mha2c_kernel<<<dim3(16, 4), 256, 0, stream>>>(partM, Wo, bo, s_out);  // s output

  // ---------------- epilogue: FFN (LN1/LN2 fused into GEMMs) ----------------
  gemm3_kernel<128, 256, 1><<<1024, 512, 0, stream>>>(out1, W1_t, b1, ffn1, nullptr, nullptr,
      nullptr, nullptr, nullptr, nullptr, M, 1024, 256);
  gemm3_kernel<64, 256, 4><<<512, 512, 0, stream>>>(ffn1, W2_t, b2, nullptr, nullptr, nullptr,
      out1, g2, be2, outp, M, 256, 1024);
  (void)in_sizes; (void)n_in; (void)out_size; (void)ws_size;
}